// Round 14
// baseline (563.103 us; speedup 1.0000x reference)
//
#include <hip/hip_runtime.h>

// Problem constants: B=16, H=8, W=32, D=512, HID=512, C=7000, T=40 (41 steps)
#define NS 41
#define LSTM_NB 64

typedef _Float16 f16x8 __attribute__((ext_vector_type(8)));
typedef float f32x4 __attribute__((ext_vector_type(4)));
typedef unsigned short ushort_t;

__device__ __forceinline__ float fsig(float x) { return 1.0f / (1.0f + __expf(-x)); }
__device__ __forceinline__ float ftanhf(float x) {
    float t = __expf(fminf(fmaxf(2.0f * x, -30.0f), 30.0f));
    return 1.0f - 2.0f / (t + 1.0f);
}

// ---------------------------------------------------------------------------
// f32 -> f16 with row padding
// ---------------------------------------------------------------------------
__launch_bounds__(256)
__global__ void cvt16(const float* __restrict__ src, ushort_t* __restrict__ dst,
                      int rows, int cols, int dcols)
{
    int total = rows * dcols;
    for (int idx = blockIdx.x * 256 + threadIdx.x; idx < total; idx += gridDim.x * 256) {
        int r = idx / dcols, c = idx - r * dcols;
        _Float16 v = (c < cols) ? (_Float16)src[(size_t)r * cols + c] : (_Float16)0.f;
        dst[idx] = __builtin_bit_cast(ushort_t, v);
    }
}

// y (624x7000) and w_lin1 (512x7000) -> one f16 [1136][7040] buffer. grid=1136
__launch_bounds__(256)
__global__ void cvt_yw(const float* __restrict__ y, const float* __restrict__ w1,
                       ushort_t* __restrict__ dst)
{
    int r = blockIdx.x;
    const float* s = (r < 624) ? (y + (size_t)r * 7000) : (w1 + (size_t)(r - 624) * 7000);
    ushort_t* d = dst + (size_t)r * 7040;
    for (int c = threadIdx.x; c < 7040; c += 256) {
        _Float16 v = (c < 7000) ? (_Float16)s[c] : (_Float16)0.f;
        d[c] = __builtin_bit_cast(ushort_t, v);
    }
}

// ---------------------------------------------------------------------------
// MFMA f16 TN GEMM body (device fn; LDS passed in: As/Bs each 64x72 f16).
// kmode: 0 = ksplit>1 -> atomicAdd; 1 = ksplit>1 -> slab z
// amode: 1 = A virtual feat: k<512 from Ah (f16, stride 512), else Af (f32).
// cmode==2: final-output remap store.
// ---------------------------------------------------------------------------
__device__ __forceinline__
void gemm16_body(_Float16* __restrict__ As, _Float16* __restrict__ Bs,
                 int bx, int by, int bz,
                 const float* __restrict__ Af, const _Float16* __restrict__ Ah,
                 const float* __restrict__ Bf, const _Float16* __restrict__ Bh,
                 float* __restrict__ C, int M, int N, int K,
                 int lda, int ldb, int ldc,
                 const float* __restrict__ bias, const float* __restrict__ bias2,
                 int cmode, int ksplit, int kmode, int slabstride, int amode)
{
    const int tid = threadIdx.x;
    const int m0 = bx * 64, n0 = by * 64;
    int ck = K, kb0 = 0;
    if (ksplit > 1) {
        ck = (((K + ksplit - 1) / ksplit) + 63) & ~63;
        kb0 = bz * ck;
    }
    const int kend = min(K, kb0 + ck);
    const int w = tid >> 6, lane = tid & 63;
    const int mh = (w >> 1) * 32, nh = (w & 1) * 32;
    const int lr = lane & 15;
    const int srow = tid >> 2, skq = tid & 3;
    const int gm = m0 + srow, gn = n0 + srow;

    f32x4 acc[2][2] = {};
    _Float16 ar[16], br[16];

    auto ldA = [&](int kb) {
        int ka = kb + skq * 16;
        if (amode == 1) {
            if (gm < M) {
                if (ka < 512) {
                    const _Float16* p = Ah + (size_t)gm * 512 + ka;
                    *(uint4*)&ar[0] = *(const uint4*)p;
                    *(uint4*)&ar[8] = *(const uint4*)(p + 8);
                } else {
                    const float* p = Af + (size_t)gm * 512 + (ka - 512);
                    float4 v0 = *(const float4*)p, v1 = *(const float4*)(p + 4);
                    float4 v2 = *(const float4*)(p + 8), v3 = *(const float4*)(p + 12);
                    ar[0]=(_Float16)v0.x; ar[1]=(_Float16)v0.y; ar[2]=(_Float16)v0.z; ar[3]=(_Float16)v0.w;
                    ar[4]=(_Float16)v1.x; ar[5]=(_Float16)v1.y; ar[6]=(_Float16)v1.z; ar[7]=(_Float16)v1.w;
                    ar[8]=(_Float16)v2.x; ar[9]=(_Float16)v2.y; ar[10]=(_Float16)v2.z; ar[11]=(_Float16)v2.w;
                    ar[12]=(_Float16)v3.x; ar[13]=(_Float16)v3.y; ar[14]=(_Float16)v3.z; ar[15]=(_Float16)v3.w;
                }
            } else {
#pragma unroll
                for (int j = 0; j < 16; ++j) ar[j] = (_Float16)0.f;
            }
            return;
        }
        if (gm < M && ka + 16 <= kend) {
            if (Ah) {
                const _Float16* p = Ah + (size_t)gm * lda + ka;
                *(uint4*)&ar[0] = *(const uint4*)p;
                *(uint4*)&ar[8] = *(const uint4*)(p + 8);
            } else {
                const float* p = Af + (size_t)gm * lda + ka;
                float4 v0 = *(const float4*)p, v1 = *(const float4*)(p + 4);
                float4 v2 = *(const float4*)(p + 8), v3 = *(const float4*)(p + 12);
                ar[0]=(_Float16)v0.x; ar[1]=(_Float16)v0.y; ar[2]=(_Float16)v0.z; ar[3]=(_Float16)v0.w;
                ar[4]=(_Float16)v1.x; ar[5]=(_Float16)v1.y; ar[6]=(_Float16)v1.z; ar[7]=(_Float16)v1.w;
                ar[8]=(_Float16)v2.x; ar[9]=(_Float16)v2.y; ar[10]=(_Float16)v2.z; ar[11]=(_Float16)v2.w;
                ar[12]=(_Float16)v3.x; ar[13]=(_Float16)v3.y; ar[14]=(_Float16)v3.z; ar[15]=(_Float16)v3.w;
            }
        } else {
#pragma unroll
            for (int j = 0; j < 16; ++j) {
                bool ok = (gm < M) && (ka + j < kend);
                ar[j] = ok ? (Ah ? Ah[(size_t)gm * lda + ka + j]
                                 : (_Float16)Af[(size_t)gm * lda + ka + j])
                           : (_Float16)0.f;
            }
        }
    };
    auto ldB = [&](int kb) {
        int ka = kb + skq * 16;
        if (gn < N && ka + 16 <= kend) {
            if (Bh) {
                const _Float16* p = Bh + (size_t)gn * ldb + ka;
                *(uint4*)&br[0] = *(const uint4*)p;
                *(uint4*)&br[8] = *(const uint4*)(p + 8);
            } else {
                const float* p = Bf + (size_t)gn * ldb + ka;
                float4 v0 = *(const float4*)p, v1 = *(const float4*)(p + 4);
                float4 v2 = *(const float4*)(p + 8), v3 = *(const float4*)(p + 12);
                br[0]=(_Float16)v0.x; br[1]=(_Float16)v0.y; br[2]=(_Float16)v0.z; br[3]=(_Float16)v0.w;
                br[4]=(_Float16)v1.x; br[5]=(_Float16)v1.y; br[6]=(_Float16)v1.z; br[7]=(_Float16)v1.w;
                br[8]=(_Float16)v2.x; br[9]=(_Float16)v2.y; br[10]=(_Float16)v2.z; br[11]=(_Float16)v2.w;
                br[12]=(_Float16)v3.x; br[13]=(_Float16)v3.y; br[14]=(_Float16)v3.z; br[15]=(_Float16)v3.w;
            }
        } else {
#pragma unroll
            for (int j = 0; j < 16; ++j) {
                bool ok = (gn < N) && (ka + j < kend);
                br[j] = ok ? (Bh ? Bh[(size_t)gn * ldb + ka + j]
                                 : (_Float16)Bf[(size_t)gn * ldb + ka + j])
                           : (_Float16)0.f;
            }
        }
    };

    ldA(kb0); ldB(kb0);
    for (int kb = kb0; kb < kend; kb += 64) {
        __syncthreads();
        *(uint4*)&As[srow * 72 + skq * 16]     = *(uint4*)&ar[0];
        *(uint4*)&As[srow * 72 + skq * 16 + 8] = *(uint4*)&ar[8];
        *(uint4*)&Bs[srow * 72 + skq * 16]     = *(uint4*)&br[0];
        *(uint4*)&Bs[srow * 72 + skq * 16 + 8] = *(uint4*)&br[8];
        __syncthreads();
        if (kb + 64 < kend) { ldA(kb + 64); ldB(kb + 64); }
#pragma unroll
        for (int kc = 0; kc < 2; ++kc) {
            int lk = (lane >> 4) * 8 + kc * 32;
            f16x8 af0 = *(const f16x8*)&As[(mh + lr) * 72 + lk];
            f16x8 af1 = *(const f16x8*)&As[(mh + 16 + lr) * 72 + lk];
            f16x8 bf0 = *(const f16x8*)&Bs[(nh + lr) * 72 + lk];
            f16x8 bf1 = *(const f16x8*)&Bs[(nh + 16 + lr) * 72 + lk];
            acc[0][0] = __builtin_amdgcn_mfma_f32_16x16x32_f16(af0, bf0, acc[0][0], 0, 0, 0);
            acc[0][1] = __builtin_amdgcn_mfma_f32_16x16x32_f16(af0, bf1, acc[0][1], 0, 0, 0);
            acc[1][0] = __builtin_amdgcn_mfma_f32_16x16x32_f16(af1, bf0, acc[1][0], 0, 0, 0);
            acc[1][1] = __builtin_amdgcn_mfma_f32_16x16x32_f16(af1, bf1, acc[1][1], 0, 0, 0);
        }
    }

#pragma unroll
    for (int mt = 0; mt < 2; ++mt)
#pragma unroll
    for (int nt = 0; nt < 2; ++nt) {
#pragma unroll
        for (int r = 0; r < 4; ++r) {
            int m = m0 + mh + mt * 16 + (lane >> 4) * 4 + r;
            int n = n0 + nh + nt * 16 + lr;
            if (m < M && n < N) {
                float v = acc[mt][nt][r];
                if (ksplit > 1) {
                    if (kmode == 1)
                        C[(size_t)bz * slabstride + (size_t)m * ldc + n] = v;
                    else
                        atomicAdd(&C[(size_t)m * ldc + n], v);
                } else {
                    if (bias)  v += bias[n];
                    if (bias2) v += bias2[n];
                    if (cmode == 2)
                        C[(size_t)(m & 15) * 280000 + (size_t)(m >> 4) * 7000 + n] = v;
                    else
                        C[(size_t)m * ldc + n] = v;
                }
            }
        }
    }
}

// standalone GEMM wrapper
__launch_bounds__(256)
__global__ void gemm16(const float* __restrict__ Af, const _Float16* __restrict__ Ah,
                       const float* __restrict__ Bf, const _Float16* __restrict__ Bh,
                       float* __restrict__ C, int M, int N, int K,
                       int lda, int ldb, int ldc,
                       const float* __restrict__ bias, const float* __restrict__ bias2,
                       int cmode, int ksplit, int kmode, int slabstride, int amode)
{
    __shared__ _Float16 smem[2 * 64 * 72];
    gemm16_body(smem, smem + 64 * 72, blockIdx.x, blockIdx.y, blockIdx.z,
                Af, Ah, Bf, Bh, C, M, N, K, lda, ldb, ldc,
                bias, bias2, cmode, ksplit, kmode, slabstride, amode);
}

// ---------------------------------------------------------------------------
// build_xs with fused slab reduction
// ---------------------------------------------------------------------------
__launch_bounds__(256)
__global__ void build_xs(const float* __restrict__ hw, const float* __restrict__ slabs,
                         const float* __restrict__ w_lin1, const float* __restrict__ b_lin1,
                         float* __restrict__ xs, int nslab)
{
    int blk = blockIdx.x;
    int t = blk >> 4, b = blk & 15;
    for (int h = threadIdx.x; h < 512; h += 256) {
        float v;
        if (t == 0)      v = hw[b * 512 + h];
        else if (t == 1) v = w_lin1[(size_t)h * 7000 + 6997] + b_lin1[h];
        else {
            size_t idx = ((size_t)b * 39 + (t - 2)) * 512 + h;
            float s = 0.f;
            for (int z = 0; z < nslab; ++z) s += slabs[(size_t)z * 319488 + idx];
            v = s + b_lin1[h];
        }
        xs[((size_t)t * 16 + b) * 512 + h] = v;
    }
}

// ---------------------------------------------------------------------------
// Fused weight prep: blocks [0,4608) conv fragments, [4608,8704) LSTM fragments
// ---------------------------------------------------------------------------
__launch_bounds__(64)
__global__ void wprep_all(const float* __restrict__ w2, ushort_t* __restrict__ wconv,
                          const float* __restrict__ Wih, const float* __restrict__ Whh,
                          ushort_t* __restrict__ wprep)
{
    const int l = threadIdx.x;
    if (blockIdx.x < 4608) {
        const int tile = blockIdx.x;
        const int dt2 = tile / 144, rem = tile - dt2 * 144;
        const int tap = rem >> 4, kc = rem & 15;
        const int d = dt2 * 16 + (l & 15);
        const int c0 = kc * 32 + (l >> 4) * 8;
        ushort_t* dst = wconv + ((size_t)tile * 64 + l) * 8;
#pragma unroll
        for (int j = 0; j < 8; ++j) {
            _Float16 v = (_Float16)w2[((size_t)d * 512 + c0 + j) * 9 + tap];
            dst[j] = __builtin_bit_cast(ushort_t, v);
        }
    } else {
        const int tile = blockIdx.x - 4608;
        const int ks = tile & 15, rt = (tile >> 4) & 1, bk = (tile >> 5) & 63, mat = tile >> 11;
        const int r = rt * 16 + (l & 15);
        const int row = (r >> 3) * 512 + bk * 8 + (r & 7);
        const int k0 = ks * 32 + (l >> 4) * 8;
        const float* src = (mat ? Whh : Wih) + (size_t)row * 512 + k0;
        ushort_t* dst = wprep + ((size_t)tile * 64 + l) * 8;
#pragma unroll
        for (int j = 0; j < 8; ++j) {
            _Float16 v = (_Float16)src[j];
            dst[j] = __builtin_bit_cast(ushort_t, v);
        }
    }
}

// ---------------------------------------------------------------------------
// MFMA 3x3 conv body (device fn; Vt2 = 340*32 f16 LDS passed in)
// ---------------------------------------------------------------------------
#define CROWS 340
__device__ __forceinline__
void conv_body(_Float16* __restrict__ Vt2, int blk,
               const float* __restrict__ V, const ushort_t* __restrict__ wconv,
               const float* __restrict__ b2, ushort_t* __restrict__ outh,
               ushort_t* __restrict__ Vh)
{
    const int b = blk >> 4, dt = blk & 15;
    const int tid = threadIdx.x;
    const int w = tid >> 6, lane = tid & 63;
    const int col = lane & 15, kg = lane >> 4;

    for (int r = tid; r < CROWS; r += 256) {
        int hh = r / 34, ww = r - hh * 34;
        if (hh == 0 || hh == 9 || ww == 0 || ww == 33) {
            uint4 z = {0u, 0u, 0u, 0u};
            *(uint4*)&Vt2[r * 32]      = z;
            *(uint4*)&Vt2[r * 32 + 8]  = z;
            *(uint4*)&Vt2[r * 32 + 16] = z;
            *(uint4*)&Vt2[r * 32 + 24] = z;
        }
    }

    int rbase[4];
#pragma unroll
    for (int nt = 0; nt < 4; ++nt) {
        int n = (w * 4 + nt) * 16 + col;
        int hh = n >> 5, ww = n & 31;
        rbase[nt] = (hh * 34 + ww) * 32 + kg * 8;
    }

    const int cc = tid & 31, pg = tid >> 5;
    f32x4 acc0[4] = {}, acc1[4] = {};

    for (int c0 = 0; c0 < 512; c0 += 32) {
        const float* s = V + (((size_t)b * 512 + c0 + cc) * 256) + pg * 32;
        const int browbase = ((pg + 1) * 34 + 1) * 32 + cc;
        _Float16 hv[32];
#pragma unroll
        for (int j4 = 0; j4 < 8; ++j4) {
            float4 v4 = *(const float4*)(s + j4 * 4);
            hv[j4 * 4 + 0] = (_Float16)v4.x;
            hv[j4 * 4 + 1] = (_Float16)v4.y;
            hv[j4 * 4 + 2] = (_Float16)v4.z;
            hv[j4 * 4 + 3] = (_Float16)v4.w;
            Vt2[browbase + (j4 * 4 + 0) * 32] = hv[j4 * 4 + 0];
            Vt2[browbase + (j4 * 4 + 1) * 32] = hv[j4 * 4 + 1];
            Vt2[browbase + (j4 * 4 + 2) * 32] = hv[j4 * 4 + 2];
            Vt2[browbase + (j4 * 4 + 3) * 32] = hv[j4 * 4 + 3];
        }
        if (Vh && dt == 0) {
            ushort_t* d = Vh + (((size_t)b * 512 + c0 + cc) * 256) + pg * 32;
#pragma unroll
            for (int q = 0; q < 4; ++q)
                *(uint4*)(d + q * 8) = *(const uint4*)&hv[q * 8];
        }
        __syncthreads();
        const int kc = c0 >> 5;
#pragma unroll
        for (int tap = 0; tap < 9; ++tap) {
            const int kh = tap / 3, kw = tap - kh * 3;
            const int toff = (kh * 34 + kw) * 32;
            f16x8 a0 = *(const f16x8*)(wconv + ((((size_t)(dt * 2 + 0) * 9 + tap) * 16 + kc) * 64 + lane) * 8);
            f16x8 a1 = *(const f16x8*)(wconv + ((((size_t)(dt * 2 + 1) * 9 + tap) * 16 + kc) * 64 + lane) * 8);
#pragma unroll
            for (int nt = 0; nt < 4; ++nt) {
                f16x8 bf = *(const f16x8*)&Vt2[rbase[nt] + toff];
                acc0[nt] = __builtin_amdgcn_mfma_f32_16x16x32_f16(a0, bf, acc0[nt], 0, 0, 0);
                acc1[nt] = __builtin_amdgcn_mfma_f32_16x16x32_f16(a1, bf, acc1[nt], 0, 0, 0);
            }
        }
        __syncthreads();
    }

    float bv0[4], bv1[4];
#pragma unroll
    for (int r = 0; r < 4; ++r) {
        bv0[r] = b2[dt * 32 + kg * 4 + r];
        bv1[r] = b2[dt * 32 + 16 + kg * 4 + r];
    }
#pragma unroll
    for (int nt = 0; nt < 4; ++nt) {
        int p = (w * 4 + nt) * 16 + col;
#pragma unroll
        for (int r = 0; r < 4; ++r) {
            int d0 = dt * 32 + kg * 4 + r;
            int d1 = d0 + 16;
            _Float16 o0 = (_Float16)(acc0[nt][r] + bv0[r]);
            _Float16 o1 = (_Float16)(acc1[nt][r] + bv1[r]);
            outh[((size_t)b * 512 + d0) * 256 + p] = __builtin_bit_cast(ushort_t, o0);
            outh[((size_t)b * 512 + d1) * 256 + p] = __builtin_bit_cast(ushort_t, o1);
        }
    }
}

// ---------------------------------------------------------------------------
// Fused g1x GEMM (blocks [0,352): 11x32 tiles) + conv (blocks [352,608))
// Both independent at this point in the schedule; one launch = concurrent.
// ---------------------------------------------------------------------------
__launch_bounds__(256)
__global__ void g1x_conv_fused(const float* __restrict__ xs, const float* __restrict__ W_ih,
                               float* __restrict__ g1x,
                               const float* __restrict__ b_ih, const float* __restrict__ b_hh,
                               const float* __restrict__ V, const ushort_t* __restrict__ wconv,
                               const float* __restrict__ b2, ushort_t* __restrict__ outh,
                               ushort_t* __restrict__ Vh)
{
    __shared__ _Float16 smem[CROWS * 32];   // 21760 B >= gemm's 2*64*72*2 = 18432 B
    if (blockIdx.x < 352) {
        int bx = blockIdx.x % 11, by = blockIdx.x / 11;
        gemm16_body(smem, smem + 64 * 72, bx, by, 0,
                    xs, nullptr, W_ih, nullptr, g1x,
                    656, 2048, 512, 512, 512, 2048,
                    b_ih, b_hh, 0, 1, 0, 0, 0);
    } else {
        conv_body(smem, blockIdx.x - 352, V, wconv, b2, outh, Vh);
    }
}

// ---------------------------------------------------------------------------
// All-poll-all grid barrier (r9-proven). Agent-scope (IC) flags; monotonic
// phases; bounded spin for hang-safety.
// ---------------------------------------------------------------------------
__device__ __forceinline__ void gbar4(unsigned* __restrict__ flags, unsigned ph)
{
    __syncthreads();   // drains vmcnt: h stores complete before flag store
    if (threadIdx.x == 0)
        __hip_atomic_store(&flags[blockIdx.x * 32], ph,
                           __ATOMIC_RELAXED, __HIP_MEMORY_SCOPE_AGENT);
    if (threadIdx.x < 64 && threadIdx.x != blockIdx.x) {
        for (int it = 0; it < 8000000; ++it) {
            if (__hip_atomic_load(&flags[threadIdx.x * 32],
                                  __ATOMIC_RELAXED, __HIP_MEMORY_SCOPE_AGENT) >= ph) break;
            __builtin_amdgcn_s_sleep(1);
        }
    }
    __syncthreads();
}

// ---------------------------------------------------------------------------
// MFMA LSTM recurrence (r9 structure, untouched)
// ---------------------------------------------------------------------------
__launch_bounds__(512, 1)
__global__ void lstm_rec(const float* __restrict__ g1x,
                         const ushort_t* __restrict__ wprep,
                         const float* __restrict__ bih,
                         const float* __restrict__ bhh,
                         ushort_t* __restrict__ h1h,   // 42 x 16 x 512 f16
                         ushort_t* __restrict__ h2h,   // 42 x 16 x 512 f16
                         unsigned* __restrict__ barflags)
{
    __shared__ _Float16 Hs1[16 * 520];
    __shared__ _Float16 Hs2[16 * 520];
    __shared__ float G1S[512];
    __shared__ float Dlds[3][32 * 17];
    __shared__ float C1S[128];
    __shared__ float C2S[128];

    const int bk = blockIdx.x;
    const int tid = threadIdx.x;
    const int w = tid >> 6, lane = tid & 63;

    if (tid < 128) { C1S[tid] = 0.f; C2S[tid] = 0.f; }

    float bs[4][2];
    if (tid >= 64 && tid < 128) {
        int up = (tid - 64) >> 4;
#pragma unroll
        for (int q = 0; q < 4; ++q)
#pragma unroll
            for (int j = 0; j < 2; ++j) {
                int u = bk * 8 + up * 2 + j;
                bs[q][j] = bih[q * 512 + u] + bhh[q * 512 + u];
            }
    }

    const int p = w >> 1, rt = w & 1;
    const int mat = (p == 1) ? 0 : 1;
    const ushort_t* wbase = wprep + (((size_t)(mat * 2048 + bk * 32 + rt * 16)) * 64 + lane) * 8;
    const int boff = (lane & 15) * 520 + (lane >> 4) * 8;
    const int drow0 = rt * 16 + (lane >> 4) * 4, dcol = lane & 15;

    for (int k = 0; k <= NS; ++k) {
        const bool doC1 = (k < NS);
        const bool doC2 = (k > 0);
        {
#pragma unroll
            for (int j = 0; j < 2; ++j) {
                int idx = tid + j * 512;
                int batch = idx >> 6, off = (idx & 63) * 8;
                uint4 v1 = *(const uint4*)(h1h + (size_t)k * 8192 + idx * 8);
                *(uint4*)(Hs1 + batch * 520 + off) = v1;
                if (doC2) {
                    uint4 v2 = *(const uint4*)(h2h + (size_t)(k - 1) * 8192 + idx * 8);
                    *(uint4*)(Hs2 + batch * 520 + off) = v2;
                }
            }
            if (doC1) {
                int r = tid >> 4, bb = tid & 15;
                int n = (r >> 3) * 512 + bk * 8 + (r & 7);
                G1S[tid] = g1x[(size_t)(k * 16 + bb) * 2048 + n];
            }
        }
        __syncthreads();
        if (w < 6 && (p == 0 ? doC1 : doC2)) {
            const _Float16* hs = (p == 2) ? Hs2 : Hs1;
            f32x4 acc = {0.f, 0.f, 0.f, 0.f};
#pragma unroll
            for (int ks = 0; ks < 16; ++ks) {
                f16x8 a = *(const f16x8*)(wbase + (size_t)ks * 512);
                f16x8 b = *(const f16x8*)(hs + boff + ks * 32);
                acc = __builtin_amdgcn_mfma_f32_16x16x32_f16(a, b, acc, 0, 0, 0);
            }
#pragma unroll
            for (int r = 0; r < 4; ++r)
                Dlds[p][(drow0 + r) * 17 + dcol] = acc[r];
        }
        __syncthreads();
        if (tid < 64) {
            if (doC1) {
                int bb = tid & 15, up = tid >> 4;
                unsigned pk = 0;
#pragma unroll
                for (int j = 0; j < 2; ++j) {
                    int ul = up * 2 + j;
                    float gi = G1S[(0 * 8 + ul) * 16 + bb] + Dlds[0][(0 * 8 + ul) * 17 + bb];
                    float gf = G1S[(1 * 8 + ul) * 16 + bb] + Dlds[0][(1 * 8 + ul) * 17 + bb];
                    float gg = G1S[(2 * 8 + ul) * 16 + bb] + Dlds[0][(2 * 8 + ul) * 17 + bb];
                    float go = G1S[(3 * 8 + ul) * 16 + bb] + Dlds[0][(3 * 8 + ul) * 17 + bb];
                    float cn = fsig(gf) * C1S[bb * 8 + ul] + fsig(gi) * ftanhf(gg);
                    C1S[bb * 8 + ul] = cn;
                    _Float16 hv = (_Float16)(fsig(go) * ftanhf(cn));
                    pk |= (unsigned)__builtin_bit_cast(ushort_t, hv) << (16 * j);
                }
                unsigned* dst = (unsigned*)h1h;
                __hip_atomic_store(&dst[(size_t)((k + 1) * 16 + bb) * 256 + bk * 4 + up],
                                   pk, __ATOMIC_RELAXED, __HIP_MEMORY_SCOPE_AGENT);
            }
        } else if (tid < 128) {
            if (doC2) {
                int t2 = tid - 64;
                int bb = t2 & 15, up = t2 >> 4;
                unsigned pk = 0;
#pragma unroll
                for (int j = 0; j < 2; ++j) {
                    int ul = up * 2 + j;
                    float gi = bs[0][j] + Dlds[1][(0 * 8 + ul) * 17 + bb] + Dlds[2][(0 * 8 + ul) * 17 + bb];
                    float gf = bs[1][j] + Dlds[1][(1 * 8 + ul) * 17 + bb] + Dlds[2][(1 * 8 + ul) * 17 + bb];
                    float gg = bs[2][j] + Dlds[1][(2 * 8 + ul) * 17 + bb] + Dlds[2][(2 * 8 + ul) * 17 + bb];
                    float go = bs[3][j] + Dlds[1][(3 * 8 + ul) * 17 + bb] + Dlds[2][(3 * 8 + ul) * 17 + bb];
                    float cn = fsig(gf) * C2S[bb * 8 + ul] + fsig(gi) * ftanhf(gg);
                    C2S[bb * 8 + ul] = cn;
                    _Float16 hv = (_Float16)(fsig(go) * ftanhf(cn));
                    pk |= (unsigned)__builtin_bit_cast(ushort_t, hv) << (16 * j);
                }
                unsigned* dst = (unsigned*)h2h;
                __hip_atomic_store(&dst[(size_t)(k * 16 + bb) * 256 + bk * 4 + up],
                                   pk, __ATOMIC_RELAXED, __HIP_MEMORY_SCOPE_AGENT);
            }
        }
        gbar4(barflags, (unsigned)(k + 1));
    }
}

// ---------------------------------------------------------------------------
// Attention with fused hproj: each block computes its own hproj row
// hp[d] = b_conv1[d] + sum_k h2[r][k] * w_conv1[d][k]  (fp32 accumulate)
// ---------------------------------------------------------------------------
__launch_bounds__(256)
__global__ void attention_k(const _Float16* __restrict__ conv2Vh,
                            const _Float16* __restrict__ h2rows,   // h2h + 32*512
                            const float* __restrict__ w1, const float* __restrict__ b1,
                            const float* __restrict__ V, const _Float16* __restrict__ Vh,
                            const float* __restrict__ w3, const float* __restrict__ b3,
                            float* __restrict__ attw_out, float* __restrict__ glimpse)
{
    const int r = blockIdx.x;
    const int to = r >> 4, b = r & 15;
    const int tid = threadIdx.x;
    const _Float16* cb = conv2Vh + (size_t)b * 512 * 256;
    __shared__ float red[256];
    __shared__ float h2F[512];
    __shared__ float hpS[512];

    const _Float16* hr = h2rows + (size_t)r * 512;
    h2F[tid]       = (float)hr[tid];
    h2F[tid + 256] = (float)hr[tid + 256];
    __syncthreads();
#pragma unroll
    for (int dl = 0; dl < 2; ++dl) {
        int d = tid + dl * 256;
        const float* wrow = w1 + (size_t)d * 512;
        float s = 0.f;
        for (int k = 0; k < 512; k += 4) {
            float4 wv = *(const float4*)(wrow + k);
            s = fmaf(wv.x, h2F[k], s);     s = fmaf(wv.y, h2F[k + 1], s);
            s = fmaf(wv.z, h2F[k + 2], s); s = fmaf(wv.w, h2F[k + 3], s);
        }
        hpS[d] = s + b1[d];
    }
    __syncthreads();

    float acc = 0.f;
#pragma unroll 4
    for (int d = 0; d < 512; ++d) {
        float x = (float)cb[(size_t)d * 256 + tid] + hpS[d];
        acc = fmaf(w3[d], ftanhf(x), acc);
    }
    float logit = acc + b3[0];
    red[tid] = logit; __syncthreads();
    for (int s = 128; s > 0; s >>= 1) { if (tid < s) red[tid] = fmaxf(red[tid], red[tid + s]); __syncthreads(); }
    float mx = red[0]; __syncthreads();
    float e = __expf(logit - mx);
    red[tid] = e; __syncthreads();
    for (int s = 128; s > 0; s >>= 1) { if (tid < s) red[tid] += red[tid + s]; __syncthreads(); }
    float aw = e / red[0];
    __syncthreads();
    attw_out[(size_t)b * 10240 + (size_t)to * 256 + tid] = aw;
    red[tid] = aw; __syncthreads();
    if (Vh) {
        const _Float16* Vb = Vh + (size_t)b * 512 * 256;
#pragma unroll
        for (int dl = 0; dl < 2; ++dl) {
            int d = tid + dl * 256;
            float g = 0.f;
            for (int p8 = 0; p8 < 256; p8 += 8) {
                f16x8 vv = *(const f16x8*)(Vb + (size_t)d * 256 + p8);
#pragma unroll
                for (int j = 0; j < 8; ++j)
                    g = fmaf((float)vv[j], red[p8 + j], g);
            }
            glimpse[(size_t)r * 512 + d] = g;
        }
    } else {
        const float* Vb = V + (size_t)b * 512 * 256;
#pragma unroll
        for (int dl = 0; dl < 2; ++dl) {
            int d = tid + dl * 256;
            float g = 0.f;
            for (int p4 = 0; p4 < 256; p4 += 4) {
                float4 vv = *(const float4*)(Vb + (size_t)d * 256 + p4);
                g = fmaf(vv.x, red[p4], g);     g = fmaf(vv.y, red[p4 + 1], g);
                g = fmaf(vv.z, red[p4 + 2], g); g = fmaf(vv.w, red[p4 + 3], g);
            }
            glimpse[(size_t)r * 512 + d] = g;
        }
    }
}

// In-place log_softmax over rows of 7000. grid = 640
__launch_bounds__(256)
__global__ void logsoftmax_k(float* __restrict__ out)
{
    int r = blockIdx.x;
    int b = r & 15, to = r >> 4;
    float* row = out + (size_t)b * 280000 + (size_t)to * 7000;
    __shared__ float buf[7000];
    __shared__ float red[256];
    int tid = threadIdx.x;
    float mx = -1e30f;
    for (int i = tid; i < 7000; i += 256) { float v = row[i]; buf[i] = v; mx = fmaxf(mx, v); }
    red[tid] = mx; __syncthreads();
    for (int s = 128; s > 0; s >>= 1) { if (tid < s) red[tid] = fmaxf(red[tid], red[tid + s]); __syncthreads(); }
    mx = red[0]; __syncthreads();
    float sm = 0.f;
    for (int i = tid; i < 7000; i += 256) sm += __expf(buf[i] - mx);
    red[tid] = sm; __syncthreads();
    for (int s = 128; s > 0; s >>= 1) { if (tid < s) red[tid] += red[tid + s]; __syncthreads(); }
    float lse = mx + __logf(red[0]);
    for (int i = tid; i < 7000; i += 256) row[i] = buf[i] - lse;
}

// ---------------------------------------------------------------------------
extern "C" void kernel_launch(void* const* d_in, const int* in_sizes, int n_in,
                              void* d_out, int out_size, void* d_ws, size_t ws_size,
                              hipStream_t stream)
{
    const float* hw      = (const float*)d_in[0];
    const float* y       = (const float*)d_in[1];
    const float* V       = (const float*)d_in[2];
    const float* w_lin1  = (const float*)d_in[3];
    const float* b_lin1  = (const float*)d_in[4];
    const float* W_ih    = (const float*)d_in[5];
    const float* b_ih    = (const float*)d_in[6];
    const float* W_hh    = (const float*)d_in[7];
    const float* b_hh    = (const float*)d_in[8];
    const float* w_conv1 = (const float*)d_in[9];
    const float* b_conv1 = (const float*)d_in[10];
    const float* w_conv2 = (const float*)d_in[11];
    const float* b_conv2 = (const float*)d_in[12];
    const float* w_conv3 = (const float*)d_in[13];
    const float* b_conv3 = (const float*)d_in[14];
    const float* w_lin2  = (const float*)d_in[15];
    const float* b_lin2  = (const float*)d_in[16];
    float* out = (float*)d_out;

    float* ws = (float*)d_ws;
    // persistent layout (float offsets) — r13-proven schedule
    float* xs_tf   = ws + 0;                         // 319,488 (fallback accum)
    unsigned* barflags = (unsigned*)(ws + 319488);   // 4,096 uints
    float* xs      = ws + 323584;                    // 335,872
    float* g1x     = ws + 659456;                    // 1,343,488
    ushort_t* conv2Vh = (ushort_t*)(ws + 2002944);   // 1,048,576 f
    ushort_t* wconv   = (ushort_t*)(ws + 3051520);   // 1,179,648 f
    float* glimpse = ws + 4558848;                   // 327,680
    ushort_t* h1h  = (ushort_t*)(ws + 5541888);      // 172,032 f
    ushort_t* h2h  = (ushort_t*)(ws + 5713920);      // 172,032 f
    float* w2lh_f  = ws + 5885952;                   // 3,584,000 -> 9,469,952
    ushort_t* w2lh = (ushort_t*)w2lh_f;
    ushort_t* Vh   = (ushort_t*)(ws + 9469952);      // 524,288 -> 9,994,240
    // transient aliases (r13 schedule)
    ushort_t* yh   = (ushort_t*)(ws + 659456);       // ..4,658,176; dead after y-gemm
    ushort_t* wlh  = (ushort_t*)(ws + 2855936);      // part of yh block
    float* slabs   = w2lh_f;                         // dead after build_xs
    ushort_t* wprep = (ushort_t*)(ws + 4231168);     // 1,048,576 f; dead after lstm
    const bool big = ws_size >= (size_t)9994240 * sizeof(float);

    // zero: xs_tf (fallback accum) + barflags; h1h/h2h slot 0
    hipMemsetAsync(ws, 0, (size_t)323584 * sizeof(float), stream);
    hipMemsetAsync(h1h, 0, 16384, stream);
    hipMemsetAsync(h2h, 0, 16384, stream);

    // y + w_lin1 -> f16 (one launch; yh/wlh contiguous)
    cvt_yw<<<1136, 256, 0, stream>>>(y, w_lin1, yh);

    // xs_tf/slabs = y @ w_lin1^T (624x512, K=7040, split-K=8)
    if (big) {
        gemm16<<<dim3(10, 8, 8), 256, 0, stream>>>(nullptr, (const _Float16*)yh,
                                                   nullptr, (const _Float16*)wlh,
                                                   slabs, 624, 512, 7040, 7040, 7040, 512,
                                                   nullptr, nullptr, 0, 8, 1, 319488, 0);
        build_xs<<<656, 256, 0, stream>>>(hw, slabs, w_lin1, b_lin1, xs, 8);
        cvt16<<<1024, 256, 0, stream>>>(w_lin2, w2lh, 7000, 1024, 1024);  // overwrites slabs
    } else {
        gemm16<<<dim3(10, 8, 8), 256, 0, stream>>>(nullptr, (const _Float16*)yh,
                                                   nullptr, (const _Float16*)wlh,
                                                   xs_tf, 624, 512, 7040, 7040, 7040, 512,
                                                   nullptr, nullptr, 0, 8, 0, 0, 0);
        build_xs<<<656, 256, 0, stream>>>(hw, xs_tf, w_lin1, b_lin1, xs, 1);
    }

    // weight preps (conv + lstm fused)
    wprep_all<<<8704, 64, 0, stream>>>(w_conv2, wconv, W_ih, W_hh, wprep);

    // fused: g1x = xs @ W_ih^T + biases  ||  conv2Vh = conv3x3(V) (+Vh persist)
    g1x_conv_fused<<<608, 256, 0, stream>>>(xs, W_ih, g1x, b_ih, b_hh,
                                            V, wconv, b_conv2, conv2Vh,
                                            big ? Vh : nullptr);

    // sequential recurrence (r9 structure)
    void* args[] = {(void*)&g1x, (void*)&wprep, (void*)&b_ih, (void*)&b_hh,
                    (void*)&h1h, (void*)&h2h, (void*)&barflags};
    hipLaunchCooperativeKernel((void*)lstm_rec, dim3(LSTM_NB), dim3(512), args, 0, stream);

    // attention with fused hproj (writes attw directly to output region)
    attention_k<<<640, 256, 0, stream>>>((const _Float16*)conv2Vh,
                                         (const _Float16*)h2h + 32 * 512,
                                         w_conv1, b_conv1, V,
                                         big ? (const _Float16*)Vh : nullptr,
                                         w_conv3, b_conv3, out + 4480000, glimpse);
    // logits: A = virtual [h2 | glimpse]; B = w_lin2 (f16 if big)
    if (big)
        gemm16<<<dim3(10, 110), 256, 0, stream>>>(glimpse, (const _Float16*)h2h + 32 * 512,
                                                  nullptr, (const _Float16*)w2lh,
                                                  out, 640, 7000, 1024, 1024, 1024, 7000,
                                                  b_lin2, nullptr, 2, 1, 0, 0, 1);
    else
        gemm16<<<dim3(10, 110), 256, 0, stream>>>(glimpse, (const _Float16*)h2h + 32 * 512,
                                                  w_lin2, nullptr,
                                                  out, 640, 7000, 1024, 1024, 1024, 7000,
                                                  b_lin2, nullptr, 2, 1, 0, 0, 1);
    logsoftmax_k<<<640, 256, 0, stream>>>(out);
}

// Round 15
// 508.326 us; speedup vs baseline: 1.1078x; 1.1078x over previous
//
#include <hip/hip_runtime.h>

// Problem constants: B=16, H=8, W=32, D=512, HID=512, C=7000, T=40 (41 steps)
#define NS 41
#define LSTM_NB 64

typedef _Float16 f16x8 __attribute__((ext_vector_type(8)));
typedef float f32x4 __attribute__((ext_vector_type(4)));
typedef unsigned short ushort_t;

__device__ __forceinline__ float fsig(float x) { return 1.0f / (1.0f + __expf(-x)); }
__device__ __forceinline__ float ftanhf(float x) {
    float t = __expf(fminf(fmaxf(2.0f * x, -30.0f), 30.0f));
    return 1.0f - 2.0f / (t + 1.0f);
}

// ---------------------------------------------------------------------------
// f32 -> f16 with row padding
// ---------------------------------------------------------------------------
__launch_bounds__(256)
__global__ void cvt16(const float* __restrict__ src, ushort_t* __restrict__ dst,
                      int rows, int cols, int dcols)
{
    int total = rows * dcols;
    for (int idx = blockIdx.x * 256 + threadIdx.x; idx < total; idx += gridDim.x * 256) {
        int r = idx / dcols, c = idx - r * dcols;
        _Float16 v = (c < cols) ? (_Float16)src[(size_t)r * cols + c] : (_Float16)0.f;
        dst[idx] = __builtin_bit_cast(ushort_t, v);
    }
}

// y (624x7000) and w_lin1 (512x7000) -> one f16 [1136][7040] buffer. grid=1136
__launch_bounds__(256)
__global__ void cvt_yw(const float* __restrict__ y, const float* __restrict__ w1,
                       ushort_t* __restrict__ dst)
{
    int r = blockIdx.x;
    const float* s = (r < 624) ? (y + (size_t)r * 7000) : (w1 + (size_t)(r - 624) * 7000);
    ushort_t* d = dst + (size_t)r * 7040;
    for (int c = threadIdx.x; c < 7040; c += 256) {
        _Float16 v = (c < 7000) ? (_Float16)s[c] : (_Float16)0.f;
        d[c] = __builtin_bit_cast(ushort_t, v);
    }
}

// ---------------------------------------------------------------------------
// MFMA f16 TN GEMM body (device fn; LDS passed in: As/Bs each 64x72 f16).
// ---------------------------------------------------------------------------
__device__ __forceinline__
void gemm16_body(_Float16* __restrict__ As, _Float16* __restrict__ Bs,
                 int bx, int by, int bz,
                 const float* __restrict__ Af, const _Float16* __restrict__ Ah,
                 const float* __restrict__ Bf, const _Float16* __restrict__ Bh,
                 float* __restrict__ C, int M, int N, int K,
                 int lda, int ldb, int ldc,
                 const float* __restrict__ bias, const float* __restrict__ bias2,
                 int cmode, int ksplit, int kmode, int slabstride, int amode)
{
    const int tid = threadIdx.x;
    const int m0 = bx * 64, n0 = by * 64;
    int ck = K, kb0 = 0;
    if (ksplit > 1) {
        ck = (((K + ksplit - 1) / ksplit) + 63) & ~63;
        kb0 = bz * ck;
    }
    const int kend = min(K, kb0 + ck);
    const int w = tid >> 6, lane = tid & 63;
    const int mh = (w >> 1) * 32, nh = (w & 1) * 32;
    const int lr = lane & 15;
    const int srow = tid >> 2, skq = tid & 3;
    const int gm = m0 + srow, gn = n0 + srow;

    f32x4 acc[2][2] = {};
    _Float16 ar[16], br[16];

    auto ldA = [&](int kb) {
        int ka = kb + skq * 16;
        if (amode == 1) {
            if (gm < M) {
                if (ka < 512) {
                    const _Float16* p = Ah + (size_t)gm * 512 + ka;
                    *(uint4*)&ar[0] = *(const uint4*)p;
                    *(uint4*)&ar[8] = *(const uint4*)(p + 8);
                } else {
                    const float* p = Af + (size_t)gm * 512 + (ka - 512);
                    float4 v0 = *(const float4*)p, v1 = *(const float4*)(p + 4);
                    float4 v2 = *(const float4*)(p + 8), v3 = *(const float4*)(p + 12);
                    ar[0]=(_Float16)v0.x; ar[1]=(_Float16)v0.y; ar[2]=(_Float16)v0.z; ar[3]=(_Float16)v0.w;
                    ar[4]=(_Float16)v1.x; ar[5]=(_Float16)v1.y; ar[6]=(_Float16)v1.z; ar[7]=(_Float16)v1.w;
                    ar[8]=(_Float16)v2.x; ar[9]=(_Float16)v2.y; ar[10]=(_Float16)v2.z; ar[11]=(_Float16)v2.w;
                    ar[12]=(_Float16)v3.x; ar[13]=(_Float16)v3.y; ar[14]=(_Float16)v3.z; ar[15]=(_Float16)v3.w;
                }
            } else {
#pragma unroll
                for (int j = 0; j < 16; ++j) ar[j] = (_Float16)0.f;
            }
            return;
        }
        if (gm < M && ka + 16 <= kend) {
            if (Ah) {
                const _Float16* p = Ah + (size_t)gm * lda + ka;
                *(uint4*)&ar[0] = *(const uint4*)p;
                *(uint4*)&ar[8] = *(const uint4*)(p + 8);
            } else {
                const float* p = Af + (size_t)gm * lda + ka;
                float4 v0 = *(const float4*)p, v1 = *(const float4*)(p + 4);
                float4 v2 = *(const float4*)(p + 8), v3 = *(const float4*)(p + 12);
                ar[0]=(_Float16)v0.x; ar[1]=(_Float16)v0.y; ar[2]=(_Float16)v0.z; ar[3]=(_Float16)v0.w;
                ar[4]=(_Float16)v1.x; ar[5]=(_Float16)v1.y; ar[6]=(_Float16)v1.z; ar[7]=(_Float16)v1.w;
                ar[8]=(_Float16)v2.x; ar[9]=(_Float16)v2.y; ar[10]=(_Float16)v2.z; ar[11]=(_Float16)v2.w;
                ar[12]=(_Float16)v3.x; ar[13]=(_Float16)v3.y; ar[14]=(_Float16)v3.z; ar[15]=(_Float16)v3.w;
            }
        } else {
#pragma unroll
            for (int j = 0; j < 16; ++j) {
                bool ok = (gm < M) && (ka + j < kend);
                ar[j] = ok ? (Ah ? Ah[(size_t)gm * lda + ka + j]
                                 : (_Float16)Af[(size_t)gm * lda + ka + j])
                           : (_Float16)0.f;
            }
        }
    };
    auto ldB = [&](int kb) {
        int ka = kb + skq * 16;
        if (gn < N && ka + 16 <= kend) {
            if (Bh) {
                const _Float16* p = Bh + (size_t)gn * ldb + ka;
                *(uint4*)&br[0] = *(const uint4*)p;
                *(uint4*)&br[8] = *(const uint4*)(p + 8);
            } else {
                const float* p = Bf + (size_t)gn * ldb + ka;
                float4 v0 = *(const float4*)p, v1 = *(const float4*)(p + 4);
                float4 v2 = *(const float4*)(p + 8), v3 = *(const float4*)(p + 12);
                br[0]=(_Float16)v0.x; br[1]=(_Float16)v0.y; br[2]=(_Float16)v0.z; br[3]=(_Float16)v0.w;
                br[4]=(_Float16)v1.x; br[5]=(_Float16)v1.y; br[6]=(_Float16)v1.z; br[7]=(_Float16)v1.w;
                br[8]=(_Float16)v2.x; br[9]=(_Float16)v2.y; br[10]=(_Float16)v2.z; br[11]=(_Float16)v2.w;
                br[12]=(_Float16)v3.x; br[13]=(_Float16)v3.y; br[14]=(_Float16)v3.z; br[15]=(_Float16)v3.w;
            }
        } else {
#pragma unroll
            for (int j = 0; j < 16; ++j) {
                bool ok = (gn < N) && (ka + j < kend);
                br[j] = ok ? (Bh ? Bh[(size_t)gn * ldb + ka + j]
                                 : (_Float16)Bf[(size_t)gn * ldb + ka + j])
                           : (_Float16)0.f;
            }
        }
    };

    ldA(kb0); ldB(kb0);
    for (int kb = kb0; kb < kend; kb += 64) {
        __syncthreads();
        *(uint4*)&As[srow * 72 + skq * 16]     = *(uint4*)&ar[0];
        *(uint4*)&As[srow * 72 + skq * 16 + 8] = *(uint4*)&ar[8];
        *(uint4*)&Bs[srow * 72 + skq * 16]     = *(uint4*)&br[0];
        *(uint4*)&Bs[srow * 72 + skq * 16 + 8] = *(uint4*)&br[8];
        __syncthreads();
        if (kb + 64 < kend) { ldA(kb + 64); ldB(kb + 64); }
#pragma unroll
        for (int kc = 0; kc < 2; ++kc) {
            int lk = (lane >> 4) * 8 + kc * 32;
            f16x8 af0 = *(const f16x8*)&As[(mh + lr) * 72 + lk];
            f16x8 af1 = *(const f16x8*)&As[(mh + 16 + lr) * 72 + lk];
            f16x8 bf0 = *(const f16x8*)&Bs[(nh + lr) * 72 + lk];
            f16x8 bf1 = *(const f16x8*)&Bs[(nh + 16 + lr) * 72 + lk];
            acc[0][0] = __builtin_amdgcn_mfma_f32_16x16x32_f16(af0, bf0, acc[0][0], 0, 0, 0);
            acc[0][1] = __builtin_amdgcn_mfma_f32_16x16x32_f16(af0, bf1, acc[0][1], 0, 0, 0);
            acc[1][0] = __builtin_amdgcn_mfma_f32_16x16x32_f16(af1, bf0, acc[1][0], 0, 0, 0);
            acc[1][1] = __builtin_amdgcn_mfma_f32_16x16x32_f16(af1, bf1, acc[1][1], 0, 0, 0);
        }
    }

#pragma unroll
    for (int mt = 0; mt < 2; ++mt)
#pragma unroll
    for (int nt = 0; nt < 2; ++nt) {
#pragma unroll
        for (int r = 0; r < 4; ++r) {
            int m = m0 + mh + mt * 16 + (lane >> 4) * 4 + r;
            int n = n0 + nh + nt * 16 + lr;
            if (m < M && n < N) {
                float v = acc[mt][nt][r];
                if (ksplit > 1) {
                    if (kmode == 1)
                        C[(size_t)bz * slabstride + (size_t)m * ldc + n] = v;
                    else
                        atomicAdd(&C[(size_t)m * ldc + n], v);
                } else {
                    if (bias)  v += bias[n];
                    if (bias2) v += bias2[n];
                    if (cmode == 2)
                        C[(size_t)(m & 15) * 280000 + (size_t)(m >> 4) * 7000 + n] = v;
                    else
                        C[(size_t)m * ldc + n] = v;
                }
            }
        }
    }
}

// standalone GEMM wrapper
__launch_bounds__(256)
__global__ void gemm16(const float* __restrict__ Af, const _Float16* __restrict__ Ah,
                       const float* __restrict__ Bf, const _Float16* __restrict__ Bh,
                       float* __restrict__ C, int M, int N, int K,
                       int lda, int ldb, int ldc,
                       const float* __restrict__ bias, const float* __restrict__ bias2,
                       int cmode, int ksplit, int kmode, int slabstride, int amode)
{
    __shared__ _Float16 smem[2 * 64 * 72];
    gemm16_body(smem, smem + 64 * 72, blockIdx.x, blockIdx.y, blockIdx.z,
                Af, Ah, Bf, Bh, C, M, N, K, lda, ldb, ldc,
                bias, bias2, cmode, ksplit, kmode, slabstride, amode);
}

// ---------------------------------------------------------------------------
// build_xs with fused slab reduction
// ---------------------------------------------------------------------------
__launch_bounds__(256)
__global__ void build_xs(const float* __restrict__ hw, const float* __restrict__ slabs,
                         const float* __restrict__ w_lin1, const float* __restrict__ b_lin1,
                         float* __restrict__ xs, int nslab)
{
    int blk = blockIdx.x;
    int t = blk >> 4, b = blk & 15;
    for (int h = threadIdx.x; h < 512; h += 256) {
        float v;
        if (t == 0)      v = hw[b * 512 + h];
        else if (t == 1) v = w_lin1[(size_t)h * 7000 + 6997] + b_lin1[h];
        else {
            size_t idx = ((size_t)b * 39 + (t - 2)) * 512 + h;
            float s = 0.f;
            for (int z = 0; z < nslab; ++z) s += slabs[(size_t)z * 319488 + idx];
            v = s + b_lin1[h];
        }
        xs[((size_t)t * 16 + b) * 512 + h] = v;
    }
}

// ---------------------------------------------------------------------------
// Fused weight prep: blocks [0,4608) conv fragments, [4608,8704) LSTM fragments
// ---------------------------------------------------------------------------
__launch_bounds__(64)
__global__ void wprep_all(const float* __restrict__ w2, ushort_t* __restrict__ wconv,
                          const float* __restrict__ Wih, const float* __restrict__ Whh,
                          ushort_t* __restrict__ wprep)
{
    const int l = threadIdx.x;
    if (blockIdx.x < 4608) {
        const int tile = blockIdx.x;
        const int dt2 = tile / 144, rem = tile - dt2 * 144;
        const int tap = rem >> 4, kc = rem & 15;
        const int d = dt2 * 16 + (l & 15);
        const int c0 = kc * 32 + (l >> 4) * 8;
        ushort_t* dst = wconv + ((size_t)tile * 64 + l) * 8;
#pragma unroll
        for (int j = 0; j < 8; ++j) {
            _Float16 v = (_Float16)w2[((size_t)d * 512 + c0 + j) * 9 + tap];
            dst[j] = __builtin_bit_cast(ushort_t, v);
        }
    } else {
        const int tile = blockIdx.x - 4608;
        const int ks = tile & 15, rt = (tile >> 4) & 1, bk = (tile >> 5) & 63, mat = tile >> 11;
        const int r = rt * 16 + (l & 15);
        const int row = (r >> 3) * 512 + bk * 8 + (r & 7);
        const int k0 = ks * 32 + (l >> 4) * 8;
        const float* src = (mat ? Whh : Wih) + (size_t)row * 512 + k0;
        ushort_t* dst = wprep + ((size_t)tile * 64 + l) * 8;
#pragma unroll
        for (int j = 0; j < 8; ++j) {
            _Float16 v = (_Float16)src[j];
            dst[j] = __builtin_bit_cast(ushort_t, v);
        }
    }
}

// ---------------------------------------------------------------------------
// MFMA 3x3 conv body (device fn; Vt2 = 340*32 f16 LDS passed in)
// ---------------------------------------------------------------------------
#define CROWS 340
__device__ __forceinline__
void conv_body(_Float16* __restrict__ Vt2, int blk,
               const float* __restrict__ V, const ushort_t* __restrict__ wconv,
               const float* __restrict__ b2, ushort_t* __restrict__ outh,
               ushort_t* __restrict__ Vh)
{
    const int b = blk >> 4, dt = blk & 15;
    const int tid = threadIdx.x;
    const int w = tid >> 6, lane = tid & 63;
    const int col = lane & 15, kg = lane >> 4;

    for (int r = tid; r < CROWS; r += 256) {
        int hh = r / 34, ww = r - hh * 34;
        if (hh == 0 || hh == 9 || ww == 0 || ww == 33) {
            uint4 z = {0u, 0u, 0u, 0u};
            *(uint4*)&Vt2[r * 32]      = z;
            *(uint4*)&Vt2[r * 32 + 8]  = z;
            *(uint4*)&Vt2[r * 32 + 16] = z;
            *(uint4*)&Vt2[r * 32 + 24] = z;
        }
    }

    int rbase[4];
#pragma unroll
    for (int nt = 0; nt < 4; ++nt) {
        int n = (w * 4 + nt) * 16 + col;
        int hh = n >> 5, ww = n & 31;
        rbase[nt] = (hh * 34 + ww) * 32 + kg * 8;
    }

    const int cc = tid & 31, pg = tid >> 5;
    f32x4 acc0[4] = {}, acc1[4] = {};

    for (int c0 = 0; c0 < 512; c0 += 32) {
        const float* s = V + (((size_t)b * 512 + c0 + cc) * 256) + pg * 32;
        const int browbase = ((pg + 1) * 34 + 1) * 32 + cc;
        _Float16 hv[32];
#pragma unroll
        for (int j4 = 0; j4 < 8; ++j4) {
            float4 v4 = *(const float4*)(s + j4 * 4);
            hv[j4 * 4 + 0] = (_Float16)v4.x;
            hv[j4 * 4 + 1] = (_Float16)v4.y;
            hv[j4 * 4 + 2] = (_Float16)v4.z;
            hv[j4 * 4 + 3] = (_Float16)v4.w;
            Vt2[browbase + (j4 * 4 + 0) * 32] = hv[j4 * 4 + 0];
            Vt2[browbase + (j4 * 4 + 1) * 32] = hv[j4 * 4 + 1];
            Vt2[browbase + (j4 * 4 + 2) * 32] = hv[j4 * 4 + 2];
            Vt2[browbase + (j4 * 4 + 3) * 32] = hv[j4 * 4 + 3];
        }
        if (Vh && dt == 0) {
            ushort_t* d = Vh + (((size_t)b * 512 + c0 + cc) * 256) + pg * 32;
#pragma unroll
            for (int q = 0; q < 4; ++q)
                *(uint4*)(d + q * 8) = *(const uint4*)&hv[q * 8];
        }
        __syncthreads();
        const int kc = c0 >> 5;
#pragma unroll
        for (int tap = 0; tap < 9; ++tap) {
            const int kh = tap / 3, kw = tap - kh * 3;
            const int toff = (kh * 34 + kw) * 32;
            f16x8 a0 = *(const f16x8*)(wconv + ((((size_t)(dt * 2 + 0) * 9 + tap) * 16 + kc) * 64 + lane) * 8);
            f16x8 a1 = *(const f16x8*)(wconv + ((((size_t)(dt * 2 + 1) * 9 + tap) * 16 + kc) * 64 + lane) * 8);
#pragma unroll
            for (int nt = 0; nt < 4; ++nt) {
                f16x8 bf = *(const f16x8*)&Vt2[rbase[nt] + toff];
                acc0[nt] = __builtin_amdgcn_mfma_f32_16x16x32_f16(a0, bf, acc0[nt], 0, 0, 0);
                acc1[nt] = __builtin_amdgcn_mfma_f32_16x16x32_f16(a1, bf, acc1[nt], 0, 0, 0);
            }
        }
        __syncthreads();
    }

    float bv0[4], bv1[4];
#pragma unroll
    for (int r = 0; r < 4; ++r) {
        bv0[r] = b2[dt * 32 + kg * 4 + r];
        bv1[r] = b2[dt * 32 + 16 + kg * 4 + r];
    }
#pragma unroll
    for (int nt = 0; nt < 4; ++nt) {
        int p = (w * 4 + nt) * 16 + col;
#pragma unroll
        for (int r = 0; r < 4; ++r) {
            int d0 = dt * 32 + kg * 4 + r;
            int d1 = d0 + 16;
            _Float16 o0 = (_Float16)(acc0[nt][r] + bv0[r]);
            _Float16 o1 = (_Float16)(acc1[nt][r] + bv1[r]);
            outh[((size_t)b * 512 + d0) * 256 + p] = __builtin_bit_cast(ushort_t, o0);
            outh[((size_t)b * 512 + d1) * 256 + p] = __builtin_bit_cast(ushort_t, o1);
        }
    }
}

// ---------------------------------------------------------------------------
// Fused g1x GEMM (blocks [0,352)) + conv (blocks [352,608)) — r14-proven
// ---------------------------------------------------------------------------
__launch_bounds__(256)
__global__ void g1x_conv_fused(const float* __restrict__ xs, const float* __restrict__ W_ih,
                               float* __restrict__ g1x,
                               const float* __restrict__ b_ih, const float* __restrict__ b_hh,
                               const float* __restrict__ V, const ushort_t* __restrict__ wconv,
                               const float* __restrict__ b2, ushort_t* __restrict__ outh,
                               ushort_t* __restrict__ Vh)
{
    __shared__ _Float16 smem[CROWS * 32];
    if (blockIdx.x < 352) {
        int bx = blockIdx.x % 11, by = blockIdx.x / 11;
        gemm16_body(smem, smem + 64 * 72, bx, by, 0,
                    xs, nullptr, W_ih, nullptr, g1x,
                    656, 2048, 512, 512, 512, 2048,
                    b_ih, b_hh, 0, 1, 0, 0, 0);
    } else {
        conv_body(smem, blockIdx.x - 352, V, wconv, b2, outh, Vh);
    }
}

// ---------------------------------------------------------------------------
// All-poll-all grid barrier (r9-proven)
// ---------------------------------------------------------------------------
__device__ __forceinline__ void gbar4(unsigned* __restrict__ flags, unsigned ph)
{
    __syncthreads();
    if (threadIdx.x == 0)
        __hip_atomic_store(&flags[blockIdx.x * 32], ph,
                           __ATOMIC_RELAXED, __HIP_MEMORY_SCOPE_AGENT);
    if (threadIdx.x < 64 && threadIdx.x != blockIdx.x) {
        for (int it = 0; it < 8000000; ++it) {
            if (__hip_atomic_load(&flags[threadIdx.x * 32],
                                  __ATOMIC_RELAXED, __HIP_MEMORY_SCOPE_AGENT) >= ph) break;
            __builtin_amdgcn_s_sleep(1);
        }
    }
    __syncthreads();
}

// ---------------------------------------------------------------------------
// MFMA LSTM recurrence (r9 structure, untouched)
// ---------------------------------------------------------------------------
__launch_bounds__(512, 1)
__global__ void lstm_rec(const float* __restrict__ g1x,
                         const ushort_t* __restrict__ wprep,
                         const float* __restrict__ bih,
                         const float* __restrict__ bhh,
                         ushort_t* __restrict__ h1h,
                         ushort_t* __restrict__ h2h,
                         unsigned* __restrict__ barflags)
{
    __shared__ _Float16 Hs1[16 * 520];
    __shared__ _Float16 Hs2[16 * 520];
    __shared__ float G1S[512];
    __shared__ float Dlds[3][32 * 17];
    __shared__ float C1S[128];
    __shared__ float C2S[128];

    const int bk = blockIdx.x;
    const int tid = threadIdx.x;
    const int w = tid >> 6, lane = tid & 63;

    if (tid < 128) { C1S[tid] = 0.f; C2S[tid] = 0.f; }

    float bs[4][2];
    if (tid >= 64 && tid < 128) {
        int up = (tid - 64) >> 4;
#pragma unroll
        for (int q = 0; q < 4; ++q)
#pragma unroll
            for (int j = 0; j < 2; ++j) {
                int u = bk * 8 + up * 2 + j;
                bs[q][j] = bih[q * 512 + u] + bhh[q * 512 + u];
            }
    }

    const int p = w >> 1, rt = w & 1;
    const int mat = (p == 1) ? 0 : 1;
    const ushort_t* wbase = wprep + (((size_t)(mat * 2048 + bk * 32 + rt * 16)) * 64 + lane) * 8;
    const int boff = (lane & 15) * 520 + (lane >> 4) * 8;
    const int drow0 = rt * 16 + (lane >> 4) * 4, dcol = lane & 15;

    for (int k = 0; k <= NS; ++k) {
        const bool doC1 = (k < NS);
        const bool doC2 = (k > 0);
        {
#pragma unroll
            for (int j = 0; j < 2; ++j) {
                int idx = tid + j * 512;
                int batch = idx >> 6, off = (idx & 63) * 8;
                uint4 v1 = *(const uint4*)(h1h + (size_t)k * 8192 + idx * 8);
                *(uint4*)(Hs1 + batch * 520 + off) = v1;
                if (doC2) {
                    uint4 v2 = *(const uint4*)(h2h + (size_t)(k - 1) * 8192 + idx * 8);
                    *(uint4*)(Hs2 + batch * 520 + off) = v2;
                }
            }
            if (doC1) {
                int r = tid >> 4, bb = tid & 15;
                int n = (r >> 3) * 512 + bk * 8 + (r & 7);
                G1S[tid] = g1x[(size_t)(k * 16 + bb) * 2048 + n];
            }
        }
        __syncthreads();
        if (w < 6 && (p == 0 ? doC1 : doC2)) {
            const _Float16* hs = (p == 2) ? Hs2 : Hs1;
            f32x4 acc = {0.f, 0.f, 0.f, 0.f};
#pragma unroll
            for (int ks = 0; ks < 16; ++ks) {
                f16x8 a = *(const f16x8*)(wbase + (size_t)ks * 512);
                f16x8 b = *(const f16x8*)(hs + boff + ks * 32);
                acc = __builtin_amdgcn_mfma_f32_16x16x32_f16(a, b, acc, 0, 0, 0);
            }
#pragma unroll
            for (int r = 0; r < 4; ++r)
                Dlds[p][(drow0 + r) * 17 + dcol] = acc[r];
        }
        __syncthreads();
        if (tid < 64) {
            if (doC1) {
                int bb = tid & 15, up = tid >> 4;
                unsigned pk = 0;
#pragma unroll
                for (int j = 0; j < 2; ++j) {
                    int ul = up * 2 + j;
                    float gi = G1S[(0 * 8 + ul) * 16 + bb] + Dlds[0][(0 * 8 + ul) * 17 + bb];
                    float gf = G1S[(1 * 8 + ul) * 16 + bb] + Dlds[0][(1 * 8 + ul) * 17 + bb];
                    float gg = G1S[(2 * 8 + ul) * 16 + bb] + Dlds[0][(2 * 8 + ul) * 17 + bb];
                    float go = G1S[(3 * 8 + ul) * 16 + bb] + Dlds[0][(3 * 8 + ul) * 17 + bb];
                    float cn = fsig(gf) * C1S[bb * 8 + ul] + fsig(gi) * ftanhf(gg);
                    C1S[bb * 8 + ul] = cn;
                    _Float16 hv = (_Float16)(fsig(go) * ftanhf(cn));
                    pk |= (unsigned)__builtin_bit_cast(ushort_t, hv) << (16 * j);
                }
                unsigned* dst = (unsigned*)h1h;
                __hip_atomic_store(&dst[(size_t)((k + 1) * 16 + bb) * 256 + bk * 4 + up],
                                   pk, __ATOMIC_RELAXED, __HIP_MEMORY_SCOPE_AGENT);
            }
        } else if (tid < 128) {
            if (doC2) {
                int t2 = tid - 64;
                int bb = t2 & 15, up = t2 >> 4;
                unsigned pk = 0;
#pragma unroll
                for (int j = 0; j < 2; ++j) {
                    int ul = up * 2 + j;
                    float gi = bs[0][j] + Dlds[1][(0 * 8 + ul) * 17 + bb] + Dlds[2][(0 * 8 + ul) * 17 + bb];
                    float gf = bs[1][j] + Dlds[1][(1 * 8 + ul) * 17 + bb] + Dlds[2][(1 * 8 + ul) * 17 + bb];
                    float gg = bs[2][j] + Dlds[1][(2 * 8 + ul) * 17 + bb] + Dlds[2][(2 * 8 + ul) * 17 + bb];
                    float go = bs[3][j] + Dlds[1][(3 * 8 + ul) * 17 + bb] + Dlds[2][(3 * 8 + ul) * 17 + bb];
                    float cn = fsig(gf) * C2S[bb * 8 + ul] + fsig(gi) * ftanhf(gg);
                    C2S[bb * 8 + ul] = cn;
                    _Float16 hv = (_Float16)(fsig(go) * ftanhf(cn));
                    pk |= (unsigned)__builtin_bit_cast(ushort_t, hv) << (16 * j);
                }
                unsigned* dst = (unsigned*)h2h;
                __hip_atomic_store(&dst[(size_t)(k * 16 + bb) * 256 + bk * 4 + up],
                                   pk, __ATOMIC_RELAXED, __HIP_MEMORY_SCOPE_AGENT);
            }
        }
        gbar4(barflags, (unsigned)(k + 1));
    }
}

// ---------------------------------------------------------------------------
// Attention (r13 form: consumes precomputed hproj)
// ---------------------------------------------------------------------------
__launch_bounds__(256)
__global__ void attention_k(const _Float16* __restrict__ conv2Vh, const float* __restrict__ hproj,
                            const float* __restrict__ V, const _Float16* __restrict__ Vh,
                            const float* __restrict__ w3, const float* __restrict__ b3,
                            float* __restrict__ attw_out, float* __restrict__ glimpse)
{
    const int r = blockIdx.x;
    const int to = r >> 4, b = r & 15;
    const int tid = threadIdx.x;
    const _Float16* cb = conv2Vh + (size_t)b * 512 * 256;
    const float* hp = hproj + (size_t)r * 512;
    __shared__ float red[256];
    float acc = 0.f;
#pragma unroll 4
    for (int d = 0; d < 512; ++d) {
        float x = (float)cb[(size_t)d * 256 + tid] + hp[d];
        acc = fmaf(w3[d], ftanhf(x), acc);
    }
    float logit = acc + b3[0];
    red[tid] = logit; __syncthreads();
    for (int s = 128; s > 0; s >>= 1) { if (tid < s) red[tid] = fmaxf(red[tid], red[tid + s]); __syncthreads(); }
    float mx = red[0]; __syncthreads();
    float e = __expf(logit - mx);
    red[tid] = e; __syncthreads();
    for (int s = 128; s > 0; s >>= 1) { if (tid < s) red[tid] += red[tid + s]; __syncthreads(); }
    float aw = e / red[0];
    __syncthreads();
    attw_out[(size_t)b * 10240 + (size_t)to * 256 + tid] = aw;
    red[tid] = aw; __syncthreads();
    if (Vh) {
        const _Float16* Vb = Vh + (size_t)b * 512 * 256;
#pragma unroll
        for (int dl = 0; dl < 2; ++dl) {
            int d = tid + dl * 256;
            float g = 0.f;
            for (int p8 = 0; p8 < 256; p8 += 8) {
                f16x8 vv = *(const f16x8*)(Vb + (size_t)d * 256 + p8);
#pragma unroll
                for (int j = 0; j < 8; ++j)
                    g = fmaf((float)vv[j], red[p8 + j], g);
            }
            glimpse[(size_t)r * 512 + d] = g;
        }
    } else {
        const float* Vb = V + (size_t)b * 512 * 256;
#pragma unroll
        for (int dl = 0; dl < 2; ++dl) {
            int d = tid + dl * 256;
            float g = 0.f;
            for (int p4 = 0; p4 < 256; p4 += 4) {
                float4 vv = *(const float4*)(Vb + (size_t)d * 256 + p4);
                g = fmaf(vv.x, red[p4], g);     g = fmaf(vv.y, red[p4 + 1], g);
                g = fmaf(vv.z, red[p4 + 2], g); g = fmaf(vv.w, red[p4 + 3], g);
            }
            glimpse[(size_t)r * 512 + d] = g;
        }
    }
}

// In-place log_softmax over rows of 7000. grid = 640
__launch_bounds__(256)
__global__ void logsoftmax_k(float* __restrict__ out)
{
    int r = blockIdx.x;
    int b = r & 15, to = r >> 4;
    float* row = out + (size_t)b * 280000 + (size_t)to * 7000;
    __shared__ float buf[7000];
    __shared__ float red[256];
    int tid = threadIdx.x;
    float mx = -1e30f;
    for (int i = tid; i < 7000; i += 256) { float v = row[i]; buf[i] = v; mx = fmaxf(mx, v); }
    red[tid] = mx; __syncthreads();
    for (int s = 128; s > 0; s >>= 1) { if (tid < s) red[tid] = fmaxf(red[tid], red[tid + s]); __syncthreads(); }
    mx = red[0]; __syncthreads();
    float sm = 0.f;
    for (int i = tid; i < 7000; i += 256) sm += __expf(buf[i] - mx);
    red[tid] = sm; __syncthreads();
    for (int s = 128; s > 0; s >>= 1) { if (tid < s) red[tid] += red[tid + s]; __syncthreads(); }
    float lse = mx + __logf(red[0]);
    for (int i = tid; i < 7000; i += 256) row[i] = buf[i] - lse;
}

// ---------------------------------------------------------------------------
extern "C" void kernel_launch(void* const* d_in, const int* in_sizes, int n_in,
                              void* d_out, int out_size, void* d_ws, size_t ws_size,
                              hipStream_t stream)
{
    const float* hw      = (const float*)d_in[0];
    const float* y       = (const float*)d_in[1];
    const float* V       = (const float*)d_in[2];
    const float* w_lin1  = (const float*)d_in[3];
    const float* b_lin1  = (const float*)d_in[4];
    const float* W_ih    = (const float*)d_in[5];
    const float* b_ih    = (const float*)d_in[6];
    const float* W_hh    = (const float*)d_in[7];
    const float* b_hh    = (const float*)d_in[8];
    const float* w_conv1 = (const float*)d_in[9];
    const float* b_conv1 = (const float*)d_in[10];
    const float* w_conv2 = (const float*)d_in[11];
    const float* b_conv2 = (const float*)d_in[12];
    const float* w_conv3 = (const float*)d_in[13];
    const float* b_conv3 = (const float*)d_in[14];
    const float* w_lin2  = (const float*)d_in[15];
    const float* b_lin2  = (const float*)d_in[16];
    float* out = (float*)d_out;

    float* ws = (float*)d_ws;
    // persistent layout (float offsets) — r13-proven schedule
    float* xs_tf   = ws + 0;                         // 319,488 (fallback accum)
    unsigned* barflags = (unsigned*)(ws + 319488);   // 4,096 uints
    float* xs      = ws + 323584;                    // 335,872
    float* g1x     = ws + 659456;                    // 1,343,488
    ushort_t* conv2Vh = (ushort_t*)(ws + 2002944);   // 1,048,576 f
    ushort_t* wconv   = (ushort_t*)(ws + 3051520);   // 1,179,648 f
    float* hproj   = ws + 4231168;                   // 327,680
    float* glimpse = ws + 4558848;                   // 327,680
    ushort_t* h1h  = (ushort_t*)(ws + 5541888);      // 172,032 f
    ushort_t* h2h  = (ushort_t*)(ws + 5713920);      // 172,032 f
    float* w2lh_f  = ws + 5885952;                   // 3,584,000 -> 9,469,952
    ushort_t* w2lh = (ushort_t*)w2lh_f;
    ushort_t* Vh   = (ushort_t*)(ws + 9469952);      // 524,288 -> 9,994,240
    // transient aliases (r13 schedule)
    ushort_t* yh   = (ushort_t*)(ws + 659456);       // dead after y-gemm
    ushort_t* wlh  = (ushort_t*)(ws + 2855936);      // part of yh block
    float* slabs   = w2lh_f;                         // dead after build_xs
    ushort_t* wprep = (ushort_t*)(ws + 4231168);     // aliases hproj; dead after lstm
    const bool big = ws_size >= (size_t)9994240 * sizeof(float);

    // zero: xs_tf (fallback accum) + barflags; h1h/h2h slot 0
    hipMemsetAsync(ws, 0, (size_t)323584 * sizeof(float), stream);
    hipMemsetAsync(h1h, 0, 16384, stream);
    hipMemsetAsync(h2h, 0, 16384, stream);

    // y + w_lin1 -> f16 (one launch; yh/wlh contiguous)
    cvt_yw<<<1136, 256, 0, stream>>>(y, w_lin1, yh);

    // xs_tf/slabs = y @ w_lin1^T (624x512, K=7040, split-K=8)
    if (big) {
        gemm16<<<dim3(10, 8, 8), 256, 0, stream>>>(nullptr, (const _Float16*)yh,
                                                   nullptr, (const _Float16*)wlh,
                                                   slabs, 624, 512, 7040, 7040, 7040, 512,
                                                   nullptr, nullptr, 0, 8, 1, 319488, 0);
        build_xs<<<656, 256, 0, stream>>>(hw, slabs, w_lin1, b_lin1, xs, 8);
        cvt16<<<1024, 256, 0, stream>>>(w_lin2, w2lh, 7000, 1024, 1024);  // overwrites slabs
    } else {
        gemm16<<<dim3(10, 8, 8), 256, 0, stream>>>(nullptr, (const _Float16*)yh,
                                                   nullptr, (const _Float16*)wlh,
                                                   xs_tf, 624, 512, 7040, 7040, 7040, 512,
                                                   nullptr, nullptr, 0, 8, 0, 0, 0);
        build_xs<<<656, 256, 0, stream>>>(hw, xs_tf, w_lin1, b_lin1, xs, 1);
    }

    // weight preps (conv + lstm fused)
    wprep_all<<<8704, 64, 0, stream>>>(w_conv2, wconv, W_ih, W_hh, wprep);

    // fused: g1x = xs @ W_ih^T + biases  ||  conv2Vh = conv3x3(V) (+Vh persist)
    g1x_conv_fused<<<608, 256, 0, stream>>>(xs, W_ih, g1x, b_ih, b_hh,
                                            V, wconv, b_conv2, conv2Vh,
                                            big ? Vh : nullptr);

    // sequential recurrence (r9 structure)
    void* args[] = {(void*)&g1x, (void*)&wprep, (void*)&b_ih, (void*)&b_hh,
                    (void*)&h1h, (void*)&h2h, (void*)&barflags};
    hipLaunchCooperativeKernel((void*)lstm_rec, dim3(LSTM_NB), dim3(512), args, 0, stream);

    // hproj = h2[1..40] @ w1^T + b_conv1  (MFMA, 80 blocks — wprep dead now)
    gemm16<<<dim3(10, 8), 256, 0, stream>>>(nullptr, (const _Float16*)h2h + 32 * 512,
                                            w_conv1, nullptr,
                                            hproj, 640, 512, 512, 512, 512, 512,
                                            b_conv1, nullptr, 0, 1, 0, 0, 0);
    // attention (writes attw directly to output region)
    attention_k<<<640, 256, 0, stream>>>((const _Float16*)conv2Vh, hproj, V,
                                         big ? (const _Float16*)Vh : nullptr,
                                         w_conv3, b_conv3, out + 4480000, glimpse);
    // logits: A = virtual [h2 | glimpse]; B = w_lin2 (f16 if big)
    if (big)
        gemm16<<<dim3(10, 110), 256, 0, stream>>>(glimpse, (const _Float16*)h2h + 32 * 512,
                                                  nullptr, (const _Float16*)w2lh,
                                                  out, 640, 7000, 1024, 1024, 1024, 7000,
                                                  b_lin2, nullptr, 2, 1, 0, 0, 1);
    else
        gemm16<<<dim3(10, 110), 256, 0, stream>>>(glimpse, (const _Float16*)h2h + 32 * 512,
                                                  w_lin2, nullptr,
                                                  out, 640, 7000, 1024, 1024, 1024, 7000,
                                                  b_lin2, nullptr, 2, 1, 0, 0, 1);
    logsoftmax_k<<<640, 256, 0, stream>>>(out);
}

// Round 16
// 486.355 us; speedup vs baseline: 1.1578x; 1.0452x over previous
//
#include <hip/hip_runtime.h>

// Problem constants: B=16, H=8, W=32, D=512, HID=512, C=7000, T=40 (41 steps)
#define NS 41
#define LSTM_NB 64

typedef _Float16 f16x8 __attribute__((ext_vector_type(8)));
typedef float f32x4 __attribute__((ext_vector_type(4)));
typedef unsigned short ushort_t;

__device__ __forceinline__ float fsig(float x) { return 1.0f / (1.0f + __expf(-x)); }
__device__ __forceinline__ float ftanhf(float x) {
    float t = __expf(fminf(fmaxf(2.0f * x, -30.0f), 30.0f));
    return 1.0f - 2.0f / (t + 1.0f);
}

// ---------------------------------------------------------------------------
// f32 -> f16 with row padding
// ---------------------------------------------------------------------------
__launch_bounds__(256)
__global__ void cvt16(const float* __restrict__ src, ushort_t* __restrict__ dst,
                      int rows, int cols, int dcols)
{
    int total = rows * dcols;
    for (int idx = blockIdx.x * 256 + threadIdx.x; idx < total; idx += gridDim.x * 256) {
        int r = idx / dcols, c = idx - r * dcols;
        _Float16 v = (c < cols) ? (_Float16)src[(size_t)r * cols + c] : (_Float16)0.f;
        dst[idx] = __builtin_bit_cast(ushort_t, v);
    }
}

// y (624x7000) and w_lin1 (512x7000) -> one f16 [1136][7040] buffer. grid=1136
__launch_bounds__(256)
__global__ void cvt_yw(const float* __restrict__ y, const float* __restrict__ w1,
                       ushort_t* __restrict__ dst)
{
    int r = blockIdx.x;
    const float* s = (r < 624) ? (y + (size_t)r * 7000) : (w1 + (size_t)(r - 624) * 7000);
    ushort_t* d = dst + (size_t)r * 7040;
    for (int c = threadIdx.x; c < 7040; c += 256) {
        _Float16 v = (c < 7000) ? (_Float16)s[c] : (_Float16)0.f;
        d[c] = __builtin_bit_cast(ushort_t, v);
    }
}

// ---------------------------------------------------------------------------
// MFMA f16 TN GEMM body (device fn; LDS passed in: As/Bs each 64x72 f16).
// ---------------------------------------------------------------------------
__device__ __forceinline__
void gemm16_body(_Float16* __restrict__ As, _Float16* __restrict__ Bs,
                 int bx, int by, int bz,
                 const float* __restrict__ Af, const _Float16* __restrict__ Ah,
                 const float* __restrict__ Bf, const _Float16* __restrict__ Bh,
                 float* __restrict__ C, int M, int N, int K,
                 int lda, int ldb, int ldc,
                 const float* __restrict__ bias, const float* __restrict__ bias2,
                 int cmode, int ksplit, int kmode, int slabstride, int amode)
{
    const int tid = threadIdx.x;
    const int m0 = bx * 64, n0 = by * 64;
    int ck = K, kb0 = 0;
    if (ksplit > 1) {
        ck = (((K + ksplit - 1) / ksplit) + 63) & ~63;
        kb0 = bz * ck;
    }
    const int kend = min(K, kb0 + ck);
    const int w = tid >> 6, lane = tid & 63;
    const int mh = (w >> 1) * 32, nh = (w & 1) * 32;
    const int lr = lane & 15;
    const int srow = tid >> 2, skq = tid & 3;
    const int gm = m0 + srow, gn = n0 + srow;

    f32x4 acc[2][2] = {};
    _Float16 ar[16], br[16];

    auto ldA = [&](int kb) {
        int ka = kb + skq * 16;
        if (amode == 1) {
            if (gm < M) {
                if (ka < 512) {
                    const _Float16* p = Ah + (size_t)gm * 512 + ka;
                    *(uint4*)&ar[0] = *(const uint4*)p;
                    *(uint4*)&ar[8] = *(const uint4*)(p + 8);
                } else {
                    const float* p = Af + (size_t)gm * 512 + (ka - 512);
                    float4 v0 = *(const float4*)p, v1 = *(const float4*)(p + 4);
                    float4 v2 = *(const float4*)(p + 8), v3 = *(const float4*)(p + 12);
                    ar[0]=(_Float16)v0.x; ar[1]=(_Float16)v0.y; ar[2]=(_Float16)v0.z; ar[3]=(_Float16)v0.w;
                    ar[4]=(_Float16)v1.x; ar[5]=(_Float16)v1.y; ar[6]=(_Float16)v1.z; ar[7]=(_Float16)v1.w;
                    ar[8]=(_Float16)v2.x; ar[9]=(_Float16)v2.y; ar[10]=(_Float16)v2.z; ar[11]=(_Float16)v2.w;
                    ar[12]=(_Float16)v3.x; ar[13]=(_Float16)v3.y; ar[14]=(_Float16)v3.z; ar[15]=(_Float16)v3.w;
                }
            } else {
#pragma unroll
                for (int j = 0; j < 16; ++j) ar[j] = (_Float16)0.f;
            }
            return;
        }
        if (gm < M && ka + 16 <= kend) {
            if (Ah) {
                const _Float16* p = Ah + (size_t)gm * lda + ka;
                *(uint4*)&ar[0] = *(const uint4*)p;
                *(uint4*)&ar[8] = *(const uint4*)(p + 8);
            } else {
                const float* p = Af + (size_t)gm * lda + ka;
                float4 v0 = *(const float4*)p, v1 = *(const float4*)(p + 4);
                float4 v2 = *(const float4*)(p + 8), v3 = *(const float4*)(p + 12);
                ar[0]=(_Float16)v0.x; ar[1]=(_Float16)v0.y; ar[2]=(_Float16)v0.z; ar[3]=(_Float16)v0.w;
                ar[4]=(_Float16)v1.x; ar[5]=(_Float16)v1.y; ar[6]=(_Float16)v1.z; ar[7]=(_Float16)v1.w;
                ar[8]=(_Float16)v2.x; ar[9]=(_Float16)v2.y; ar[10]=(_Float16)v2.z; ar[11]=(_Float16)v2.w;
                ar[12]=(_Float16)v3.x; ar[13]=(_Float16)v3.y; ar[14]=(_Float16)v3.z; ar[15]=(_Float16)v3.w;
            }
        } else {
#pragma unroll
            for (int j = 0; j < 16; ++j) {
                bool ok = (gm < M) && (ka + j < kend);
                ar[j] = ok ? (Ah ? Ah[(size_t)gm * lda + ka + j]
                                 : (_Float16)Af[(size_t)gm * lda + ka + j])
                           : (_Float16)0.f;
            }
        }
    };
    auto ldB = [&](int kb) {
        int ka = kb + skq * 16;
        if (gn < N && ka + 16 <= kend) {
            if (Bh) {
                const _Float16* p = Bh + (size_t)gn * ldb + ka;
                *(uint4*)&br[0] = *(const uint4*)p;
                *(uint4*)&br[8] = *(const uint4*)(p + 8);
            } else {
                const float* p = Bf + (size_t)gn * ldb + ka;
                float4 v0 = *(const float4*)p, v1 = *(const float4*)(p + 4);
                float4 v2 = *(const float4*)(p + 8), v3 = *(const float4*)(p + 12);
                br[0]=(_Float16)v0.x; br[1]=(_Float16)v0.y; br[2]=(_Float16)v0.z; br[3]=(_Float16)v0.w;
                br[4]=(_Float16)v1.x; br[5]=(_Float16)v1.y; br[6]=(_Float16)v1.z; br[7]=(_Float16)v1.w;
                br[8]=(_Float16)v2.x; br[9]=(_Float16)v2.y; br[10]=(_Float16)v2.z; br[11]=(_Float16)v2.w;
                br[12]=(_Float16)v3.x; br[13]=(_Float16)v3.y; br[14]=(_Float16)v3.z; br[15]=(_Float16)v3.w;
            }
        } else {
#pragma unroll
            for (int j = 0; j < 16; ++j) {
                bool ok = (gn < N) && (ka + j < kend);
                br[j] = ok ? (Bh ? Bh[(size_t)gn * ldb + ka + j]
                                 : (_Float16)Bf[(size_t)gn * ldb + ka + j])
                           : (_Float16)0.f;
            }
        }
    };

    ldA(kb0); ldB(kb0);
    for (int kb = kb0; kb < kend; kb += 64) {
        __syncthreads();
        *(uint4*)&As[srow * 72 + skq * 16]     = *(uint4*)&ar[0];
        *(uint4*)&As[srow * 72 + skq * 16 + 8] = *(uint4*)&ar[8];
        *(uint4*)&Bs[srow * 72 + skq * 16]     = *(uint4*)&br[0];
        *(uint4*)&Bs[srow * 72 + skq * 16 + 8] = *(uint4*)&br[8];
        __syncthreads();
        if (kb + 64 < kend) { ldA(kb + 64); ldB(kb + 64); }
#pragma unroll
        for (int kc = 0; kc < 2; ++kc) {
            int lk = (lane >> 4) * 8 + kc * 32;
            f16x8 af0 = *(const f16x8*)&As[(mh + lr) * 72 + lk];
            f16x8 af1 = *(const f16x8*)&As[(mh + 16 + lr) * 72 + lk];
            f16x8 bf0 = *(const f16x8*)&Bs[(nh + lr) * 72 + lk];
            f16x8 bf1 = *(const f16x8*)&Bs[(nh + 16 + lr) * 72 + lk];
            acc[0][0] = __builtin_amdgcn_mfma_f32_16x16x32_f16(af0, bf0, acc[0][0], 0, 0, 0);
            acc[0][1] = __builtin_amdgcn_mfma_f32_16x16x32_f16(af0, bf1, acc[0][1], 0, 0, 0);
            acc[1][0] = __builtin_amdgcn_mfma_f32_16x16x32_f16(af1, bf0, acc[1][0], 0, 0, 0);
            acc[1][1] = __builtin_amdgcn_mfma_f32_16x16x32_f16(af1, bf1, acc[1][1], 0, 0, 0);
        }
    }

#pragma unroll
    for (int mt = 0; mt < 2; ++mt)
#pragma unroll
    for (int nt = 0; nt < 2; ++nt) {
#pragma unroll
        for (int r = 0; r < 4; ++r) {
            int m = m0 + mh + mt * 16 + (lane >> 4) * 4 + r;
            int n = n0 + nh + nt * 16 + lr;
            if (m < M && n < N) {
                float v = acc[mt][nt][r];
                if (ksplit > 1) {
                    if (kmode == 1)
                        C[(size_t)bz * slabstride + (size_t)m * ldc + n] = v;
                    else
                        atomicAdd(&C[(size_t)m * ldc + n], v);
                } else {
                    if (bias)  v += bias[n];
                    if (bias2) v += bias2[n];
                    if (cmode == 2)
                        C[(size_t)(m & 15) * 280000 + (size_t)(m >> 4) * 7000 + n] = v;
                    else
                        C[(size_t)m * ldc + n] = v;
                }
            }
        }
    }
}

// standalone GEMM wrapper
__launch_bounds__(256)
__global__ void gemm16(const float* __restrict__ Af, const _Float16* __restrict__ Ah,
                       const float* __restrict__ Bf, const _Float16* __restrict__ Bh,
                       float* __restrict__ C, int M, int N, int K,
                       int lda, int ldb, int ldc,
                       const float* __restrict__ bias, const float* __restrict__ bias2,
                       int cmode, int ksplit, int kmode, int slabstride, int amode)
{
    __shared__ _Float16 smem[2 * 64 * 72];
    gemm16_body(smem, smem + 64 * 72, blockIdx.x, blockIdx.y, blockIdx.z,
                Af, Ah, Bf, Bh, C, M, N, K, lda, ldb, ldc,
                bias, bias2, cmode, ksplit, kmode, slabstride, amode);
}

// ---------------------------------------------------------------------------
// build_xs with fused slab reduction
// ---------------------------------------------------------------------------
__launch_bounds__(256)
__global__ void build_xs(const float* __restrict__ hw, const float* __restrict__ slabs,
                         const float* __restrict__ w_lin1, const float* __restrict__ b_lin1,
                         float* __restrict__ xs, int nslab)
{
    int blk = blockIdx.x;
    int t = blk >> 4, b = blk & 15;
    for (int h = threadIdx.x; h < 512; h += 256) {
        float v;
        if (t == 0)      v = hw[b * 512 + h];
        else if (t == 1) v = w_lin1[(size_t)h * 7000 + 6997] + b_lin1[h];
        else {
            size_t idx = ((size_t)b * 39 + (t - 2)) * 512 + h;
            float s = 0.f;
            for (int z = 0; z < nslab; ++z) s += slabs[(size_t)z * 319488 + idx];
            v = s + b_lin1[h];
        }
        xs[((size_t)t * 16 + b) * 512 + h] = v;
    }
}

// ---------------------------------------------------------------------------
// Fused weight prep: blocks [0,4608) conv fragments, [4608,8704) LSTM fragments
// ---------------------------------------------------------------------------
__launch_bounds__(64)
__global__ void wprep_all(const float* __restrict__ w2, ushort_t* __restrict__ wconv,
                          const float* __restrict__ Wih, const float* __restrict__ Whh,
                          ushort_t* __restrict__ wprep)
{
    const int l = threadIdx.x;
    if (blockIdx.x < 4608) {
        const int tile = blockIdx.x;
        const int dt2 = tile / 144, rem = tile - dt2 * 144;
        const int tap = rem >> 4, kc = rem & 15;
        const int d = dt2 * 16 + (l & 15);
        const int c0 = kc * 32 + (l >> 4) * 8;
        ushort_t* dst = wconv + ((size_t)tile * 64 + l) * 8;
#pragma unroll
        for (int j = 0; j < 8; ++j) {
            _Float16 v = (_Float16)w2[((size_t)d * 512 + c0 + j) * 9 + tap];
            dst[j] = __builtin_bit_cast(ushort_t, v);
        }
    } else {
        const int tile = blockIdx.x - 4608;
        const int ks = tile & 15, rt = (tile >> 4) & 1, bk = (tile >> 5) & 63, mat = tile >> 11;
        const int r = rt * 16 + (l & 15);
        const int row = (r >> 3) * 512 + bk * 8 + (r & 7);
        const int k0 = ks * 32 + (l >> 4) * 8;
        const float* src = (mat ? Whh : Wih) + (size_t)row * 512 + k0;
        ushort_t* dst = wprep + ((size_t)tile * 64 + l) * 8;
#pragma unroll
        for (int j = 0; j < 8; ++j) {
            _Float16 v = (_Float16)src[j];
            dst[j] = __builtin_bit_cast(ushort_t, v);
        }
    }
}

// ---------------------------------------------------------------------------
// MFMA 3x3 conv body (device fn; Vt2 = 340*32 f16 LDS passed in)
// ---------------------------------------------------------------------------
#define CROWS 340
__device__ __forceinline__
void conv_body(_Float16* __restrict__ Vt2, int blk,
               const float* __restrict__ V, const ushort_t* __restrict__ wconv,
               const float* __restrict__ b2, ushort_t* __restrict__ outh,
               ushort_t* __restrict__ Vh)
{
    const int b = blk >> 4, dt = blk & 15;
    const int tid = threadIdx.x;
    const int w = tid >> 6, lane = tid & 63;
    const int col = lane & 15, kg = lane >> 4;

    for (int r = tid; r < CROWS; r += 256) {
        int hh = r / 34, ww = r - hh * 34;
        if (hh == 0 || hh == 9 || ww == 0 || ww == 33) {
            uint4 z = {0u, 0u, 0u, 0u};
            *(uint4*)&Vt2[r * 32]      = z;
            *(uint4*)&Vt2[r * 32 + 8]  = z;
            *(uint4*)&Vt2[r * 32 + 16] = z;
            *(uint4*)&Vt2[r * 32 + 24] = z;
        }
    }

    int rbase[4];
#pragma unroll
    for (int nt = 0; nt < 4; ++nt) {
        int n = (w * 4 + nt) * 16 + col;
        int hh = n >> 5, ww = n & 31;
        rbase[nt] = (hh * 34 + ww) * 32 + kg * 8;
    }

    const int cc = tid & 31, pg = tid >> 5;
    f32x4 acc0[4] = {}, acc1[4] = {};

    for (int c0 = 0; c0 < 512; c0 += 32) {
        const float* s = V + (((size_t)b * 512 + c0 + cc) * 256) + pg * 32;
        const int browbase = ((pg + 1) * 34 + 1) * 32 + cc;
        _Float16 hv[32];
#pragma unroll
        for (int j4 = 0; j4 < 8; ++j4) {
            float4 v4 = *(const float4*)(s + j4 * 4);
            hv[j4 * 4 + 0] = (_Float16)v4.x;
            hv[j4 * 4 + 1] = (_Float16)v4.y;
            hv[j4 * 4 + 2] = (_Float16)v4.z;
            hv[j4 * 4 + 3] = (_Float16)v4.w;
            Vt2[browbase + (j4 * 4 + 0) * 32] = hv[j4 * 4 + 0];
            Vt2[browbase + (j4 * 4 + 1) * 32] = hv[j4 * 4 + 1];
            Vt2[browbase + (j4 * 4 + 2) * 32] = hv[j4 * 4 + 2];
            Vt2[browbase + (j4 * 4 + 3) * 32] = hv[j4 * 4 + 3];
        }
        if (Vh && dt == 0) {
            ushort_t* d = Vh + (((size_t)b * 512 + c0 + cc) * 256) + pg * 32;
#pragma unroll
            for (int q = 0; q < 4; ++q)
                *(uint4*)(d + q * 8) = *(const uint4*)&hv[q * 8];
        }
        __syncthreads();
        const int kc = c0 >> 5;
#pragma unroll
        for (int tap = 0; tap < 9; ++tap) {
            const int kh = tap / 3, kw = tap - kh * 3;
            const int toff = (kh * 34 + kw) * 32;
            f16x8 a0 = *(const f16x8*)(wconv + ((((size_t)(dt * 2 + 0) * 9 + tap) * 16 + kc) * 64 + lane) * 8);
            f16x8 a1 = *(const f16x8*)(wconv + ((((size_t)(dt * 2 + 1) * 9 + tap) * 16 + kc) * 64 + lane) * 8);
#pragma unroll
            for (int nt = 0; nt < 4; ++nt) {
                f16x8 bf = *(const f16x8*)&Vt2[rbase[nt] + toff];
                acc0[nt] = __builtin_amdgcn_mfma_f32_16x16x32_f16(a0, bf, acc0[nt], 0, 0, 0);
                acc1[nt] = __builtin_amdgcn_mfma_f32_16x16x32_f16(a1, bf, acc1[nt], 0, 0, 0);
            }
        }
        __syncthreads();
    }

    float bv0[4], bv1[4];
#pragma unroll
    for (int r = 0; r < 4; ++r) {
        bv0[r] = b2[dt * 32 + kg * 4 + r];
        bv1[r] = b2[dt * 32 + 16 + kg * 4 + r];
    }
#pragma unroll
    for (int nt = 0; nt < 4; ++nt) {
        int p = (w * 4 + nt) * 16 + col;
#pragma unroll
        for (int r = 0; r < 4; ++r) {
            int d0 = dt * 32 + kg * 4 + r;
            int d1 = d0 + 16;
            _Float16 o0 = (_Float16)(acc0[nt][r] + bv0[r]);
            _Float16 o1 = (_Float16)(acc1[nt][r] + bv1[r]);
            outh[((size_t)b * 512 + d0) * 256 + p] = __builtin_bit_cast(ushort_t, o0);
            outh[((size_t)b * 512 + d1) * 256 + p] = __builtin_bit_cast(ushort_t, o1);
        }
    }
}

// ---------------------------------------------------------------------------
// Fused g1x GEMM (blocks [0,352)) + conv (blocks [352,608)) — r14-proven
// ---------------------------------------------------------------------------
__launch_bounds__(256)
__global__ void g1x_conv_fused(const float* __restrict__ xs, const float* __restrict__ W_ih,
                               float* __restrict__ g1x,
                               const float* __restrict__ b_ih, const float* __restrict__ b_hh,
                               const float* __restrict__ V, const ushort_t* __restrict__ wconv,
                               const float* __restrict__ b2, ushort_t* __restrict__ outh,
                               ushort_t* __restrict__ Vh)
{
    __shared__ _Float16 smem[CROWS * 32];
    if (blockIdx.x < 352) {
        int bx = blockIdx.x % 11, by = blockIdx.x / 11;
        gemm16_body(smem, smem + 64 * 72, bx, by, 0,
                    xs, nullptr, W_ih, nullptr, g1x,
                    656, 2048, 512, 512, 512, 2048,
                    b_ih, b_hh, 0, 1, 0, 0, 0);
    } else {
        conv_body(smem, blockIdx.x - 352, V, wconv, b2, outh, Vh);
    }
}

// ---------------------------------------------------------------------------
// All-poll-all grid barrier (r9-proven)
// ---------------------------------------------------------------------------
__device__ __forceinline__ void gbar4(unsigned* __restrict__ flags, unsigned ph)
{
    __syncthreads();
    if (threadIdx.x == 0)
        __hip_atomic_store(&flags[blockIdx.x * 32], ph,
                           __ATOMIC_RELAXED, __HIP_MEMORY_SCOPE_AGENT);
    if (threadIdx.x < 64 && threadIdx.x != blockIdx.x) {
        for (int it = 0; it < 8000000; ++it) {
            if (__hip_atomic_load(&flags[threadIdx.x * 32],
                                  __ATOMIC_RELAXED, __HIP_MEMORY_SCOPE_AGENT) >= ph) break;
            __builtin_amdgcn_s_sleep(1);
        }
    }
    __syncthreads();
}

// ---------------------------------------------------------------------------
// MFMA LSTM recurrence (r9 structure, untouched)
// ---------------------------------------------------------------------------
__launch_bounds__(512, 1)
__global__ void lstm_rec(const float* __restrict__ g1x,
                         const ushort_t* __restrict__ wprep,
                         const float* __restrict__ bih,
                         const float* __restrict__ bhh,
                         ushort_t* __restrict__ h1h,
                         ushort_t* __restrict__ h2h,
                         unsigned* __restrict__ barflags)
{
    __shared__ _Float16 Hs1[16 * 520];
    __shared__ _Float16 Hs2[16 * 520];
    __shared__ float G1S[512];
    __shared__ float Dlds[3][32 * 17];
    __shared__ float C1S[128];
    __shared__ float C2S[128];

    const int bk = blockIdx.x;
    const int tid = threadIdx.x;
    const int w = tid >> 6, lane = tid & 63;

    if (tid < 128) { C1S[tid] = 0.f; C2S[tid] = 0.f; }

    float bs[4][2];
    if (tid >= 64 && tid < 128) {
        int up = (tid - 64) >> 4;
#pragma unroll
        for (int q = 0; q < 4; ++q)
#pragma unroll
            for (int j = 0; j < 2; ++j) {
                int u = bk * 8 + up * 2 + j;
                bs[q][j] = bih[q * 512 + u] + bhh[q * 512 + u];
            }
    }

    const int p = w >> 1, rt = w & 1;
    const int mat = (p == 1) ? 0 : 1;
    const ushort_t* wbase = wprep + (((size_t)(mat * 2048 + bk * 32 + rt * 16)) * 64 + lane) * 8;
    const int boff = (lane & 15) * 520 + (lane >> 4) * 8;
    const int drow0 = rt * 16 + (lane >> 4) * 4, dcol = lane & 15;

    for (int k = 0; k <= NS; ++k) {
        const bool doC1 = (k < NS);
        const bool doC2 = (k > 0);
        {
#pragma unroll
            for (int j = 0; j < 2; ++j) {
                int idx = tid + j * 512;
                int batch = idx >> 6, off = (idx & 63) * 8;
                uint4 v1 = *(const uint4*)(h1h + (size_t)k * 8192 + idx * 8);
                *(uint4*)(Hs1 + batch * 520 + off) = v1;
                if (doC2) {
                    uint4 v2 = *(const uint4*)(h2h + (size_t)(k - 1) * 8192 + idx * 8);
                    *(uint4*)(Hs2 + batch * 520 + off) = v2;
                }
            }
            if (doC1) {
                int r = tid >> 4, bb = tid & 15;
                int n = (r >> 3) * 512 + bk * 8 + (r & 7);
                G1S[tid] = g1x[(size_t)(k * 16 + bb) * 2048 + n];
            }
        }
        __syncthreads();
        if (w < 6 && (p == 0 ? doC1 : doC2)) {
            const _Float16* hs = (p == 2) ? Hs2 : Hs1;
            f32x4 acc = {0.f, 0.f, 0.f, 0.f};
#pragma unroll
            for (int ks = 0; ks < 16; ++ks) {
                f16x8 a = *(const f16x8*)(wbase + (size_t)ks * 512);
                f16x8 b = *(const f16x8*)(hs + boff + ks * 32);
                acc = __builtin_amdgcn_mfma_f32_16x16x32_f16(a, b, acc, 0, 0, 0);
            }
#pragma unroll
            for (int r = 0; r < 4; ++r)
                Dlds[p][(drow0 + r) * 17 + dcol] = acc[r];
        }
        __syncthreads();
        if (tid < 64) {
            if (doC1) {
                int bb = tid & 15, up = tid >> 4;
                unsigned pk = 0;
#pragma unroll
                for (int j = 0; j < 2; ++j) {
                    int ul = up * 2 + j;
                    float gi = G1S[(0 * 8 + ul) * 16 + bb] + Dlds[0][(0 * 8 + ul) * 17 + bb];
                    float gf = G1S[(1 * 8 + ul) * 16 + bb] + Dlds[0][(1 * 8 + ul) * 17 + bb];
                    float gg = G1S[(2 * 8 + ul) * 16 + bb] + Dlds[0][(2 * 8 + ul) * 17 + bb];
                    float go = G1S[(3 * 8 + ul) * 16 + bb] + Dlds[0][(3 * 8 + ul) * 17 + bb];
                    float cn = fsig(gf) * C1S[bb * 8 + ul] + fsig(gi) * ftanhf(gg);
                    C1S[bb * 8 + ul] = cn;
                    _Float16 hv = (_Float16)(fsig(go) * ftanhf(cn));
                    pk |= (unsigned)__builtin_bit_cast(ushort_t, hv) << (16 * j);
                }
                unsigned* dst = (unsigned*)h1h;
                __hip_atomic_store(&dst[(size_t)((k + 1) * 16 + bb) * 256 + bk * 4 + up],
                                   pk, __ATOMIC_RELAXED, __HIP_MEMORY_SCOPE_AGENT);
            }
        } else if (tid < 128) {
            if (doC2) {
                int t2 = tid - 64;
                int bb = t2 & 15, up = t2 >> 4;
                unsigned pk = 0;
#pragma unroll
                for (int j = 0; j < 2; ++j) {
                    int ul = up * 2 + j;
                    float gi = bs[0][j] + Dlds[1][(0 * 8 + ul) * 17 + bb] + Dlds[2][(0 * 8 + ul) * 17 + bb];
                    float gf = bs[1][j] + Dlds[1][(1 * 8 + ul) * 17 + bb] + Dlds[2][(1 * 8 + ul) * 17 + bb];
                    float gg = bs[2][j] + Dlds[1][(2 * 8 + ul) * 17 + bb] + Dlds[2][(2 * 8 + ul) * 17 + bb];
                    float go = bs[3][j] + Dlds[1][(3 * 8 + ul) * 17 + bb] + Dlds[2][(3 * 8 + ul) * 17 + bb];
                    float cn = fsig(gf) * C2S[bb * 8 + ul] + fsig(gi) * ftanhf(gg);
                    C2S[bb * 8 + ul] = cn;
                    _Float16 hv = (_Float16)(fsig(go) * ftanhf(cn));
                    pk |= (unsigned)__builtin_bit_cast(ushort_t, hv) << (16 * j);
                }
                unsigned* dst = (unsigned*)h2h;
                __hip_atomic_store(&dst[(size_t)(k * 16 + bb) * 256 + bk * 4 + up],
                                   pk, __ATOMIC_RELAXED, __HIP_MEMORY_SCOPE_AGENT);
            }
        }
        gbar4(barflags, (unsigned)(k + 1));
    }
}

// ---------------------------------------------------------------------------
// Attention — LDS-staged logits. Per 64-d chunk: cooperative f16x8 loads of
// conv2Vh (coalesced, 8 vector loads/thread) with hproj[d] folded in at stage
// time; tanh/FMA reduction reads LDS (low latency) with 4 independent accs.
// ---------------------------------------------------------------------------
__launch_bounds__(256)
__global__ void attention_k(const _Float16* __restrict__ conv2Vh, const float* __restrict__ hproj,
                            const float* __restrict__ V, const _Float16* __restrict__ Vh,
                            const float* __restrict__ w3, const float* __restrict__ b3,
                            float* __restrict__ attw_out, float* __restrict__ glimpse)
{
    const int r = blockIdx.x;
    const int to = r >> 4, b = r & 15;
    const int tid = threadIdx.x;
    const _Float16* cb = conv2Vh + (size_t)b * 512 * 256;
    const float* hp = hproj + (size_t)r * 512;
    __shared__ _Float16 stg[64 * 264];
    __shared__ float w3S[512];
    __shared__ float red[256];

    w3S[tid]       = w3[tid];
    w3S[tid + 256] = w3[tid + 256];

    const int dl0 = tid >> 5;        // 0..7
    const int pp  = (tid & 31) * 8;  // 0..248

    float a0 = 0.f, a1 = 0.f, a2 = 0.f, a3 = 0.f;
    for (int chunk = 0; chunk < 8; ++chunk) {
        const int dbase = chunk * 64;
        __syncthreads();             // stg free (and w3S visible on first iter)
#pragma unroll
        for (int j = 0; j < 8; ++j) {
            int dl = j * 8 + dl0;
            int d = dbase + dl;
            f16x8 cv = *(const f16x8*)(cb + (size_t)d * 256 + pp);
            float hpd = hp[d];
            f16x8 t;
#pragma unroll
            for (int e = 0; e < 8; ++e) t[e] = (_Float16)((float)cv[e] + hpd);
            *(f16x8*)&stg[dl * 264 + pp] = t;
        }
        __syncthreads();
#pragma unroll 4
        for (int dl = 0; dl < 64; dl += 4) {
            float x0 = (float)stg[(dl + 0) * 264 + tid];
            float x1 = (float)stg[(dl + 1) * 264 + tid];
            float x2 = (float)stg[(dl + 2) * 264 + tid];
            float x3 = (float)stg[(dl + 3) * 264 + tid];
            a0 = fmaf(w3S[dbase + dl + 0], ftanhf(x0), a0);
            a1 = fmaf(w3S[dbase + dl + 1], ftanhf(x1), a1);
            a2 = fmaf(w3S[dbase + dl + 2], ftanhf(x2), a2);
            a3 = fmaf(w3S[dbase + dl + 3], ftanhf(x3), a3);
        }
    }
    float logit = (a0 + a1) + (a2 + a3) + b3[0];
    __syncthreads();
    red[tid] = logit; __syncthreads();
    for (int s = 128; s > 0; s >>= 1) { if (tid < s) red[tid] = fmaxf(red[tid], red[tid + s]); __syncthreads(); }
    float mx = red[0]; __syncthreads();
    float e = __expf(logit - mx);
    red[tid] = e; __syncthreads();
    for (int s = 128; s > 0; s >>= 1) { if (tid < s) red[tid] += red[tid + s]; __syncthreads(); }
    float aw = e / red[0];
    __syncthreads();
    attw_out[(size_t)b * 10240 + (size_t)to * 256 + tid] = aw;
    red[tid] = aw; __syncthreads();
    if (Vh) {
        const _Float16* Vb = Vh + (size_t)b * 512 * 256;
#pragma unroll
        for (int dl = 0; dl < 2; ++dl) {
            int d = tid + dl * 256;
            float g = 0.f;
            for (int p8 = 0; p8 < 256; p8 += 8) {
                f16x8 vv = *(const f16x8*)(Vb + (size_t)d * 256 + p8);
#pragma unroll
                for (int j = 0; j < 8; ++j)
                    g = fmaf((float)vv[j], red[p8 + j], g);
            }
            glimpse[(size_t)r * 512 + d] = g;
        }
    } else {
        const float* Vb = V + (size_t)b * 512 * 256;
#pragma unroll
        for (int dl = 0; dl < 2; ++dl) {
            int d = tid + dl * 256;
            float g = 0.f;
            for (int p4 = 0; p4 < 256; p4 += 4) {
                float4 vv = *(const float4*)(Vb + (size_t)d * 256 + p4);
                g = fmaf(vv.x, red[p4], g);     g = fmaf(vv.y, red[p4 + 1], g);
                g = fmaf(vv.z, red[p4 + 2], g); g = fmaf(vv.w, red[p4 + 3], g);
            }
            glimpse[(size_t)r * 512 + d] = g;
        }
    }
}

// In-place log_softmax over rows of 7000. grid = 640
__launch_bounds__(256)
__global__ void logsoftmax_k(float* __restrict__ out)
{
    int r = blockIdx.x;
    int b = r & 15, to = r >> 4;
    float* row = out + (size_t)b * 280000 + (size_t)to * 7000;
    __shared__ float buf[7000];
    __shared__ float red[256];
    int tid = threadIdx.x;
    float mx = -1e30f;
    for (int i = tid; i < 7000; i += 256) { float v = row[i]; buf[i] = v; mx = fmaxf(mx, v); }
    red[tid] = mx; __syncthreads();
    for (int s = 128; s > 0; s >>= 1) { if (tid < s) red[tid] = fmaxf(red[tid], red[tid + s]); __syncthreads(); }
    mx = red[0]; __syncthreads();
    float sm = 0.f;
    for (int i = tid; i < 7000; i += 256) sm += __expf(buf[i] - mx);
    red[tid] = sm; __syncthreads();
    for (int s = 128; s > 0; s >>= 1) { if (tid < s) red[tid] += red[tid + s]; __syncthreads(); }
    float lse = mx + __logf(red[0]);
    for (int i = tid; i < 7000; i += 256) row[i] = buf[i] - lse;
}

// ---------------------------------------------------------------------------
extern "C" void kernel_launch(void* const* d_in, const int* in_sizes, int n_in,
                              void* d_out, int out_size, void* d_ws, size_t ws_size,
                              hipStream_t stream)
{
    const float* hw      = (const float*)d_in[0];
    const float* y       = (const float*)d_in[1];
    const float* V       = (const float*)d_in[2];
    const float* w_lin1  = (const float*)d_in[3];
    const float* b_lin1  = (const float*)d_in[4];
    const float* W_ih    = (const float*)d_in[5];
    const float* b_ih    = (const float*)d_in[6];
    const float* W_hh    = (const float*)d_in[7];
    const float* b_hh    = (const float*)d_in[8];
    const float* w_conv1 = (const float*)d_in[9];
    const float* b_conv1 = (const float*)d_in[10];
    const float* w_conv2 = (const float*)d_in[11];
    const float* b_conv2 = (const float*)d_in[12];
    const float* w_conv3 = (const float*)d_in[13];
    const float* b_conv3 = (const float*)d_in[14];
    const float* w_lin2  = (const float*)d_in[15];
    const float* b_lin2  = (const float*)d_in[16];
    float* out = (float*)d_out;

    float* ws = (float*)d_ws;
    // persistent layout (float offsets) — r13/r15-proven schedule
    float* xs_tf   = ws + 0;                         // 319,488 (fallback accum)
    unsigned* barflags = (unsigned*)(ws + 319488);   // 4,096 uints
    float* xs      = ws + 323584;                    // 335,872
    float* g1x     = ws + 659456;                    // 1,343,488
    ushort_t* conv2Vh = (ushort_t*)(ws + 2002944);   // 1,048,576 f
    ushort_t* wconv   = (ushort_t*)(ws + 3051520);   // 1,179,648 f
    float* hproj   = ws + 4231168;                   // 327,680
    float* glimpse = ws + 4558848;                   // 327,680
    ushort_t* h1h  = (ushort_t*)(ws + 5541888);      // 172,032 f
    ushort_t* h2h  = (ushort_t*)(ws + 5713920);      // 172,032 f
    float* w2lh_f  = ws + 5885952;                   // 3,584,000 -> 9,469,952
    ushort_t* w2lh = (ushort_t*)w2lh_f;
    ushort_t* Vh   = (ushort_t*)(ws + 9469952);      // 524,288 -> 9,994,240
    // transient aliases (r13 schedule)
    ushort_t* yh   = (ushort_t*)(ws + 659456);       // dead after y-gemm
    ushort_t* wlh  = (ushort_t*)(ws + 2855936);      // part of yh block
    float* slabs   = w2lh_f;                         // dead after build_xs
    ushort_t* wprep = (ushort_t*)(ws + 4231168);     // aliases hproj; dead after lstm
    const bool big = ws_size >= (size_t)9994240 * sizeof(float);

    // zero: xs_tf (fallback accum) + barflags; h1h/h2h slot 0
    hipMemsetAsync(ws, 0, (size_t)323584 * sizeof(float), stream);
    hipMemsetAsync(h1h, 0, 16384, stream);
    hipMemsetAsync(h2h, 0, 16384, stream);

    // y + w_lin1 -> f16 (one launch; yh/wlh contiguous)
    cvt_yw<<<1136, 256, 0, stream>>>(y, w_lin1, yh);

    // xs_tf/slabs = y @ w_lin1^T (624x512, K=7040, split-K=8)
    if (big) {
        gemm16<<<dim3(10, 8, 8), 256, 0, stream>>>(nullptr, (const _Float16*)yh,
                                                   nullptr, (const _Float16*)wlh,
                                                   slabs, 624, 512, 7040, 7040, 7040, 512,
                                                   nullptr, nullptr, 0, 8, 1, 319488, 0);
        build_xs<<<656, 256, 0, stream>>>(hw, slabs, w_lin1, b_lin1, xs, 8);
        cvt16<<<1024, 256, 0, stream>>>(w_lin2, w2lh, 7000, 1024, 1024);  // overwrites slabs
    } else {
        gemm16<<<dim3(10, 8, 8), 256, 0, stream>>>(nullptr, (const _Float16*)yh,
                                                   nullptr, (const _Float16*)wlh,
                                                   xs_tf, 624, 512, 7040, 7040, 7040, 512,
                                                   nullptr, nullptr, 0, 8, 0, 0, 0);
        build_xs<<<656, 256, 0, stream>>>(hw, xs_tf, w_lin1, b_lin1, xs, 1);
    }

    // weight preps (conv + lstm fused)
    wprep_all<<<8704, 64, 0, stream>>>(w_conv2, wconv, W_ih, W_hh, wprep);

    // fused: g1x = xs @ W_ih^T + biases  ||  conv2Vh = conv3x3(V) (+Vh persist)
    g1x_conv_fused<<<608, 256, 0, stream>>>(xs, W_ih, g1x, b_ih, b_hh,
                                            V, wconv, b_conv2, conv2Vh,
                                            big ? Vh : nullptr);

    // sequential recurrence (r9 structure)
    void* args[] = {(void*)&g1x, (void*)&wprep, (void*)&b_ih, (void*)&b_hh,
                    (void*)&h1h, (void*)&h2h, (void*)&barflags};
    hipLaunchCooperativeKernel((void*)lstm_rec, dim3(LSTM_NB), dim3(512), args, 0, stream);

    // hproj = h2[1..40] @ w1^T + b_conv1  (MFMA, 80 blocks — wprep dead now)
    gemm16<<<dim3(10, 8), 256, 0, stream>>>(nullptr, (const _Float16*)h2h + 32 * 512,
                                            w_conv1, nullptr,
                                            hproj, 640, 512, 512, 512, 512, 512,
                                            b_conv1, nullptr, 0, 1, 0, 0, 0);
    // attention (LDS-staged; writes attw directly to output region)
    attention_k<<<640, 256, 0, stream>>>((const _Float16*)conv2Vh, hproj, V,
                                         big ? (const _Float16*)Vh : nullptr,
                                         w_conv3, b_conv3, out + 4480000, glimpse);
    // logits: A = virtual [h2 | glimpse]; B = w_lin2 (f16 if big)
    if (big)
        gemm16<<<dim3(10, 110), 256, 0, stream>>>(glimpse, (const _Float16*)h2h + 32 * 512,
                                                  nullptr, (const _Float16*)w2lh,
                                                  out, 640, 7000, 1024, 1024, 1024, 7000,
                                                  b_lin2, nullptr, 2, 1, 0, 0, 1);
    else
        gemm16<<<dim3(10, 110), 256, 0, stream>>>(glimpse, (const _Float16*)h2h + 32 * 512,
                                                  w_lin2, nullptr,
                                                  out, 640, 7000, 1024, 1024, 1024, 7000,
                                                  b_lin2, nullptr, 2, 1, 0, 0, 1);
    logsoftmax_k<<<640, 256, 0, stream>>>(out);
}

// Round 17
// 470.546 us; speedup vs baseline: 1.1967x; 1.0336x over previous
//
#include <hip/hip_runtime.h>

// Problem constants: B=16, H=8, W=32, D=512, HID=512, C=7000, T=40 (41 steps)
#define NS 41
#define LSTM_NB 64

typedef _Float16 f16x8 __attribute__((ext_vector_type(8)));
typedef float f32x4 __attribute__((ext_vector_type(4)));
typedef unsigned short ushort_t;

__device__ __forceinline__ float fsig(float x) { return 1.0f / (1.0f + __expf(-x)); }
__device__ __forceinline__ float ftanhf(float x) {
    float t = __expf(fminf(fmaxf(2.0f * x, -30.0f), 30.0f));
    return 1.0f - 2.0f / (t + 1.0f);
}

// ---------------------------------------------------------------------------
// f32 -> f16 with row padding
// ---------------------------------------------------------------------------
__launch_bounds__(256)
__global__ void cvt16(const float* __restrict__ src, ushort_t* __restrict__ dst,
                      int rows, int cols, int dcols)
{
    int total = rows * dcols;
    for (int idx = blockIdx.x * 256 + threadIdx.x; idx < total; idx += gridDim.x * 256) {
        int r = idx / dcols, c = idx - r * dcols;
        _Float16 v = (c < cols) ? (_Float16)src[(size_t)r * cols + c] : (_Float16)0.f;
        dst[idx] = __builtin_bit_cast(ushort_t, v);
    }
}

// ---------------------------------------------------------------------------
// MEGA-PREP: one launch fusing all independent input prep.
//  blocks [0,1136): y/w_lin1 -> f16 [1136][7040]
//  blocks [1136,3312): conv+lstm weight fragment prep (4 tiles/block)
//  block 3312: zero barflags (4096 uints) + h1h slot0 + h2h slot0
// ---------------------------------------------------------------------------
__launch_bounds__(256)
__global__ void mega_prep(const float* __restrict__ y, const float* __restrict__ w1,
                          ushort_t* __restrict__ yw_dst,
                          const float* __restrict__ w2, ushort_t* __restrict__ wconv,
                          const float* __restrict__ Wih, const float* __restrict__ Whh,
                          ushort_t* __restrict__ wprep,
                          unsigned* __restrict__ barflags,
                          ushort_t* __restrict__ h1h, ushort_t* __restrict__ h2h)
{
    const int blk = blockIdx.x;
    const int tid = threadIdx.x;
    if (blk < 1136) {
        // cvt_yw
        const float* s = (blk < 624) ? (y + (size_t)blk * 7000)
                                     : (w1 + (size_t)(blk - 624) * 7000);
        ushort_t* d = yw_dst + (size_t)blk * 7040;
        for (int c = tid; c < 7040; c += 256) {
            _Float16 v = (c < 7000) ? (_Float16)s[c] : (_Float16)0.f;
            d[c] = __builtin_bit_cast(ushort_t, v);
        }
    } else if (blk < 3312) {
        // weight fragment prep: 4 tiles per block
        const int tile = (blk - 1136) * 4 + (tid >> 6);
        const int l = tid & 63;
        if (tile < 4608) {
            const int dt2 = tile / 144, rem = tile - dt2 * 144;
            const int tap = rem >> 4, kc = rem & 15;
            const int d = dt2 * 16 + (l & 15);
            const int c0 = kc * 32 + (l >> 4) * 8;
            ushort_t* dst = wconv + ((size_t)tile * 64 + l) * 8;
#pragma unroll
            for (int j = 0; j < 8; ++j) {
                _Float16 v = (_Float16)w2[((size_t)d * 512 + c0 + j) * 9 + tap];
                dst[j] = __builtin_bit_cast(ushort_t, v);
            }
        } else {
            const int t2 = tile - 4608;
            const int ks = t2 & 15, rt = (t2 >> 4) & 1, bk = (t2 >> 5) & 63, mat = t2 >> 11;
            const int r = rt * 16 + (l & 15);
            const int row = (r >> 3) * 512 + bk * 8 + (r & 7);
            const int k0 = ks * 32 + (l >> 4) * 8;
            const float* src = (mat ? Whh : Wih) + (size_t)row * 512 + k0;
            ushort_t* dst = wprep + ((size_t)t2 * 64 + l) * 8;
#pragma unroll
            for (int j = 0; j < 8; ++j) {
                _Float16 v = (_Float16)src[j];
                dst[j] = __builtin_bit_cast(ushort_t, v);
            }
        }
    } else {
        // zeroing: barflags (4096 uints), h1h slot0 + h2h slot0 (4096 uints each)
        for (int i = tid; i < 4096; i += 256) barflags[i] = 0u;
        unsigned* z1 = (unsigned*)h1h;
        unsigned* z2 = (unsigned*)h2h;
        for (int i = tid; i < 4096; i += 256) { z1[i] = 0u; z2[i] = 0u; }
    }
}

// ---------------------------------------------------------------------------
// MFMA f16 TN GEMM body (device fn; LDS passed in: As/Bs each 64x72 f16).
// ---------------------------------------------------------------------------
__device__ __forceinline__
void gemm16_body(_Float16* __restrict__ As, _Float16* __restrict__ Bs,
                 int bx, int by, int bz,
                 const float* __restrict__ Af, const _Float16* __restrict__ Ah,
                 const float* __restrict__ Bf, const _Float16* __restrict__ Bh,
                 float* __restrict__ C, int M, int N, int K,
                 int lda, int ldb, int ldc,
                 const float* __restrict__ bias, const float* __restrict__ bias2,
                 int cmode, int ksplit, int kmode, int slabstride, int amode)
{
    const int tid = threadIdx.x;
    const int m0 = bx * 64, n0 = by * 64;
    int ck = K, kb0 = 0;
    if (ksplit > 1) {
        ck = (((K + ksplit - 1) / ksplit) + 63) & ~63;
        kb0 = bz * ck;
    }
    const int kend = min(K, kb0 + ck);
    const int w = tid >> 6, lane = tid & 63;
    const int mh = (w >> 1) * 32, nh = (w & 1) * 32;
    const int lr = lane & 15;
    const int srow = tid >> 2, skq = tid & 3;
    const int gm = m0 + srow, gn = n0 + srow;

    f32x4 acc[2][2] = {};
    _Float16 ar[16], br[16];

    auto ldA = [&](int kb) {
        int ka = kb + skq * 16;
        if (amode == 1) {
            if (gm < M) {
                if (ka < 512) {
                    const _Float16* p = Ah + (size_t)gm * 512 + ka;
                    *(uint4*)&ar[0] = *(const uint4*)p;
                    *(uint4*)&ar[8] = *(const uint4*)(p + 8);
                } else {
                    const float* p = Af + (size_t)gm * 512 + (ka - 512);
                    float4 v0 = *(const float4*)p, v1 = *(const float4*)(p + 4);
                    float4 v2 = *(const float4*)(p + 8), v3 = *(const float4*)(p + 12);
                    ar[0]=(_Float16)v0.x; ar[1]=(_Float16)v0.y; ar[2]=(_Float16)v0.z; ar[3]=(_Float16)v0.w;
                    ar[4]=(_Float16)v1.x; ar[5]=(_Float16)v1.y; ar[6]=(_Float16)v1.z; ar[7]=(_Float16)v1.w;
                    ar[8]=(_Float16)v2.x; ar[9]=(_Float16)v2.y; ar[10]=(_Float16)v2.z; ar[11]=(_Float16)v2.w;
                    ar[12]=(_Float16)v3.x; ar[13]=(_Float16)v3.y; ar[14]=(_Float16)v3.z; ar[15]=(_Float16)v3.w;
                }
            } else {
#pragma unroll
                for (int j = 0; j < 16; ++j) ar[j] = (_Float16)0.f;
            }
            return;
        }
        if (gm < M && ka + 16 <= kend) {
            if (Ah) {
                const _Float16* p = Ah + (size_t)gm * lda + ka;
                *(uint4*)&ar[0] = *(const uint4*)p;
                *(uint4*)&ar[8] = *(const uint4*)(p + 8);
            } else {
                const float* p = Af + (size_t)gm * lda + ka;
                float4 v0 = *(const float4*)p, v1 = *(const float4*)(p + 4);
                float4 v2 = *(const float4*)(p + 8), v3 = *(const float4*)(p + 12);
                ar[0]=(_Float16)v0.x; ar[1]=(_Float16)v0.y; ar[2]=(_Float16)v0.z; ar[3]=(_Float16)v0.w;
                ar[4]=(_Float16)v1.x; ar[5]=(_Float16)v1.y; ar[6]=(_Float16)v1.z; ar[7]=(_Float16)v1.w;
                ar[8]=(_Float16)v2.x; ar[9]=(_Float16)v2.y; ar[10]=(_Float16)v2.z; ar[11]=(_Float16)v2.w;
                ar[12]=(_Float16)v3.x; ar[13]=(_Float16)v3.y; ar[14]=(_Float16)v3.z; ar[15]=(_Float16)v3.w;
            }
        } else {
#pragma unroll
            for (int j = 0; j < 16; ++j) {
                bool ok = (gm < M) && (ka + j < kend);
                ar[j] = ok ? (Ah ? Ah[(size_t)gm * lda + ka + j]
                                 : (_Float16)Af[(size_t)gm * lda + ka + j])
                           : (_Float16)0.f;
            }
        }
    };
    auto ldB = [&](int kb) {
        int ka = kb + skq * 16;
        if (gn < N && ka + 16 <= kend) {
            if (Bh) {
                const _Float16* p = Bh + (size_t)gn * ldb + ka;
                *(uint4*)&br[0] = *(const uint4*)p;
                *(uint4*)&br[8] = *(const uint4*)(p + 8);
            } else {
                const float* p = Bf + (size_t)gn * ldb + ka;
                float4 v0 = *(const float4*)p, v1 = *(const float4*)(p + 4);
                float4 v2 = *(const float4*)(p + 8), v3 = *(const float4*)(p + 12);
                br[0]=(_Float16)v0.x; br[1]=(_Float16)v0.y; br[2]=(_Float16)v0.z; br[3]=(_Float16)v0.w;
                br[4]=(_Float16)v1.x; br[5]=(_Float16)v1.y; br[6]=(_Float16)v1.z; br[7]=(_Float16)v1.w;
                br[8]=(_Float16)v2.x; br[9]=(_Float16)v2.y; br[10]=(_Float16)v2.z; br[11]=(_Float16)v2.w;
                br[12]=(_Float16)v3.x; br[13]=(_Float16)v3.y; br[14]=(_Float16)v3.z; br[15]=(_Float16)v3.w;
            }
        } else {
#pragma unroll
            for (int j = 0; j < 16; ++j) {
                bool ok = (gn < N) && (ka + j < kend);
                br[j] = ok ? (Bh ? Bh[(size_t)gn * ldb + ka + j]
                                 : (_Float16)Bf[(size_t)gn * ldb + ka + j])
                           : (_Float16)0.f;
            }
        }
    };

    ldA(kb0); ldB(kb0);
    for (int kb = kb0; kb < kend; kb += 64) {
        __syncthreads();
        *(uint4*)&As[srow * 72 + skq * 16]     = *(uint4*)&ar[0];
        *(uint4*)&As[srow * 72 + skq * 16 + 8] = *(uint4*)&ar[8];
        *(uint4*)&Bs[srow * 72 + skq * 16]     = *(uint4*)&br[0];
        *(uint4*)&Bs[srow * 72 + skq * 16 + 8] = *(uint4*)&br[8];
        __syncthreads();
        if (kb + 64 < kend) { ldA(kb + 64); ldB(kb + 64); }
#pragma unroll
        for (int kc = 0; kc < 2; ++kc) {
            int lk = (lane >> 4) * 8 + kc * 32;
            f16x8 af0 = *(const f16x8*)&As[(mh + lr) * 72 + lk];
            f16x8 af1 = *(const f16x8*)&As[(mh + 16 + lr) * 72 + lk];
            f16x8 bf0 = *(const f16x8*)&Bs[(nh + lr) * 72 + lk];
            f16x8 bf1 = *(const f16x8*)&Bs[(nh + 16 + lr) * 72 + lk];
            acc[0][0] = __builtin_amdgcn_mfma_f32_16x16x32_f16(af0, bf0, acc[0][0], 0, 0, 0);
            acc[0][1] = __builtin_amdgcn_mfma_f32_16x16x32_f16(af0, bf1, acc[0][1], 0, 0, 0);
            acc[1][0] = __builtin_amdgcn_mfma_f32_16x16x32_f16(af1, bf0, acc[1][0], 0, 0, 0);
            acc[1][1] = __builtin_amdgcn_mfma_f32_16x16x32_f16(af1, bf1, acc[1][1], 0, 0, 0);
        }
    }

#pragma unroll
    for (int mt = 0; mt < 2; ++mt)
#pragma unroll
    for (int nt = 0; nt < 2; ++nt) {
#pragma unroll
        for (int r = 0; r < 4; ++r) {
            int m = m0 + mh + mt * 16 + (lane >> 4) * 4 + r;
            int n = n0 + nh + nt * 16 + lr;
            if (m < M && n < N) {
                float v = acc[mt][nt][r];
                if (ksplit > 1) {
                    if (kmode == 1)
                        C[(size_t)bz * slabstride + (size_t)m * ldc + n] = v;
                    else
                        atomicAdd(&C[(size_t)m * ldc + n], v);
                } else {
                    if (bias)  v += bias[n];
                    if (bias2) v += bias2[n];
                    if (cmode == 2)
                        C[(size_t)(m & 15) * 280000 + (size_t)(m >> 4) * 7000 + n] = v;
                    else
                        C[(size_t)m * ldc + n] = v;
                }
            }
        }
    }
}

// standalone GEMM wrapper
__launch_bounds__(256)
__global__ void gemm16(const float* __restrict__ Af, const _Float16* __restrict__ Ah,
                       const float* __restrict__ Bf, const _Float16* __restrict__ Bh,
                       float* __restrict__ C, int M, int N, int K,
                       int lda, int ldb, int ldc,
                       const float* __restrict__ bias, const float* __restrict__ bias2,
                       int cmode, int ksplit, int kmode, int slabstride, int amode)
{
    __shared__ _Float16 smem[2 * 64 * 72];
    gemm16_body(smem, smem + 64 * 72, blockIdx.x, blockIdx.y, blockIdx.z,
                Af, Ah, Bf, Bh, C, M, N, K, lda, ldb, ldc,
                bias, bias2, cmode, ksplit, kmode, slabstride, amode);
}

// ---------------------------------------------------------------------------
// build_xs with fused slab reduction
// ---------------------------------------------------------------------------
__launch_bounds__(256)
__global__ void build_xs(const float* __restrict__ hw, const float* __restrict__ slabs,
                         const float* __restrict__ w_lin1, const float* __restrict__ b_lin1,
                         float* __restrict__ xs, int nslab)
{
    int blk = blockIdx.x;
    int t = blk >> 4, b = blk & 15;
    for (int h = threadIdx.x; h < 512; h += 256) {
        float v;
        if (t == 0)      v = hw[b * 512 + h];
        else if (t == 1) v = w_lin1[(size_t)h * 7000 + 6997] + b_lin1[h];
        else {
            size_t idx = ((size_t)b * 39 + (t - 2)) * 512 + h;
            float s = 0.f;
            for (int z = 0; z < nslab; ++z) s += slabs[(size_t)z * 319488 + idx];
            v = s + b_lin1[h];
        }
        xs[((size_t)t * 16 + b) * 512 + h] = v;
    }
}

// ---------------------------------------------------------------------------
// MFMA 3x3 conv body (device fn; Vt2 = 340*32 f16 LDS passed in)
// ---------------------------------------------------------------------------
#define CROWS 340
__device__ __forceinline__
void conv_body(_Float16* __restrict__ Vt2, int blk,
               const float* __restrict__ V, const ushort_t* __restrict__ wconv,
               const float* __restrict__ b2, ushort_t* __restrict__ outh,
               ushort_t* __restrict__ Vh)
{
    const int b = blk >> 4, dt = blk & 15;
    const int tid = threadIdx.x;
    const int w = tid >> 6, lane = tid & 63;
    const int col = lane & 15, kg = lane >> 4;

    for (int r = tid; r < CROWS; r += 256) {
        int hh = r / 34, ww = r - hh * 34;
        if (hh == 0 || hh == 9 || ww == 0 || ww == 33) {
            uint4 z = {0u, 0u, 0u, 0u};
            *(uint4*)&Vt2[r * 32]      = z;
            *(uint4*)&Vt2[r * 32 + 8]  = z;
            *(uint4*)&Vt2[r * 32 + 16] = z;
            *(uint4*)&Vt2[r * 32 + 24] = z;
        }
    }

    int rbase[4];
#pragma unroll
    for (int nt = 0; nt < 4; ++nt) {
        int n = (w * 4 + nt) * 16 + col;
        int hh = n >> 5, ww = n & 31;
        rbase[nt] = (hh * 34 + ww) * 32 + kg * 8;
    }

    const int cc = tid & 31, pg = tid >> 5;
    f32x4 acc0[4] = {}, acc1[4] = {};

    for (int c0 = 0; c0 < 512; c0 += 32) {
        const float* s = V + (((size_t)b * 512 + c0 + cc) * 256) + pg * 32;
        const int browbase = ((pg + 1) * 34 + 1) * 32 + cc;
        _Float16 hv[32];
#pragma unroll
        for (int j4 = 0; j4 < 8; ++j4) {
            float4 v4 = *(const float4*)(s + j4 * 4);
            hv[j4 * 4 + 0] = (_Float16)v4.x;
            hv[j4 * 4 + 1] = (_Float16)v4.y;
            hv[j4 * 4 + 2] = (_Float16)v4.z;
            hv[j4 * 4 + 3] = (_Float16)v4.w;
            Vt2[browbase + (j4 * 4 + 0) * 32] = hv[j4 * 4 + 0];
            Vt2[browbase + (j4 * 4 + 1) * 32] = hv[j4 * 4 + 1];
            Vt2[browbase + (j4 * 4 + 2) * 32] = hv[j4 * 4 + 2];
            Vt2[browbase + (j4 * 4 + 3) * 32] = hv[j4 * 4 + 3];
        }
        if (Vh && dt == 0) {
            ushort_t* d = Vh + (((size_t)b * 512 + c0 + cc) * 256) + pg * 32;
#pragma unroll
            for (int q = 0; q < 4; ++q)
                *(uint4*)(d + q * 8) = *(const uint4*)&hv[q * 8];
        }
        __syncthreads();
        const int kc = c0 >> 5;
#pragma unroll
        for (int tap = 0; tap < 9; ++tap) {
            const int kh = tap / 3, kw = tap - kh * 3;
            const int toff = (kh * 34 + kw) * 32;
            f16x8 a0 = *(const f16x8*)(wconv + ((((size_t)(dt * 2 + 0) * 9 + tap) * 16 + kc) * 64 + lane) * 8);
            f16x8 a1 = *(const f16x8*)(wconv + ((((size_t)(dt * 2 + 1) * 9 + tap) * 16 + kc) * 64 + lane) * 8);
#pragma unroll
            for (int nt = 0; nt < 4; ++nt) {
                f16x8 bf = *(const f16x8*)&Vt2[rbase[nt] + toff];
                acc0[nt] = __builtin_amdgcn_mfma_f32_16x16x32_f16(a0, bf, acc0[nt], 0, 0, 0);
                acc1[nt] = __builtin_amdgcn_mfma_f32_16x16x32_f16(a1, bf, acc1[nt], 0, 0, 0);
            }
        }
        __syncthreads();
    }

    float bv0[4], bv1[4];
#pragma unroll
    for (int r = 0; r < 4; ++r) {
        bv0[r] = b2[dt * 32 + kg * 4 + r];
        bv1[r] = b2[dt * 32 + 16 + kg * 4 + r];
    }
#pragma unroll
    for (int nt = 0; nt < 4; ++nt) {
        int p = (w * 4 + nt) * 16 + col;
#pragma unroll
        for (int r = 0; r < 4; ++r) {
            int d0 = dt * 32 + kg * 4 + r;
            int d1 = d0 + 16;
            _Float16 o0 = (_Float16)(acc0[nt][r] + bv0[r]);
            _Float16 o1 = (_Float16)(acc1[nt][r] + bv1[r]);
            outh[((size_t)b * 512 + d0) * 256 + p] = __builtin_bit_cast(ushort_t, o0);
            outh[((size_t)b * 512 + d1) * 256 + p] = __builtin_bit_cast(ushort_t, o1);
        }
    }
}

// ---------------------------------------------------------------------------
// Fused g1x GEMM (blocks [0,352)) + conv (blocks [352,608)) — r14-proven
// ---------------------------------------------------------------------------
__launch_bounds__(256)
__global__ void g1x_conv_fused(const float* __restrict__ xs, const float* __restrict__ W_ih,
                               float* __restrict__ g1x,
                               const float* __restrict__ b_ih, const float* __restrict__ b_hh,
                               const float* __restrict__ V, const ushort_t* __restrict__ wconv,
                               const float* __restrict__ b2, ushort_t* __restrict__ outh,
                               ushort_t* __restrict__ Vh)
{
    __shared__ _Float16 smem[CROWS * 32];
    if (blockIdx.x < 352) {
        int bx = blockIdx.x % 11, by = blockIdx.x / 11;
        gemm16_body(smem, smem + 64 * 72, bx, by, 0,
                    xs, nullptr, W_ih, nullptr, g1x,
                    656, 2048, 512, 512, 512, 2048,
                    b_ih, b_hh, 0, 1, 0, 0, 0);
    } else {
        conv_body(smem, blockIdx.x - 352, V, wconv, b2, outh, Vh);
    }
}

// ---------------------------------------------------------------------------
// All-poll-all grid barrier (r9-proven)
// ---------------------------------------------------------------------------
__device__ __forceinline__ void gbar4(unsigned* __restrict__ flags, unsigned ph)
{
    __syncthreads();
    if (threadIdx.x == 0)
        __hip_atomic_store(&flags[blockIdx.x * 32], ph,
                           __ATOMIC_RELAXED, __HIP_MEMORY_SCOPE_AGENT);
    if (threadIdx.x < 64 && threadIdx.x != blockIdx.x) {
        for (int it = 0; it < 8000000; ++it) {
            if (__hip_atomic_load(&flags[threadIdx.x * 32],
                                  __ATOMIC_RELAXED, __HIP_MEMORY_SCOPE_AGENT) >= ph) break;
            __builtin_amdgcn_s_sleep(1);
        }
    }
    __syncthreads();
}

// ---------------------------------------------------------------------------
// MFMA LSTM recurrence (r9 structure, untouched)
// ---------------------------------------------------------------------------
__launch_bounds__(512, 1)
__global__ void lstm_rec(const float* __restrict__ g1x,
                         const ushort_t* __restrict__ wprep,
                         const float* __restrict__ bih,
                         const float* __restrict__ bhh,
                         ushort_t* __restrict__ h1h,
                         ushort_t* __restrict__ h2h,
                         unsigned* __restrict__ barflags)
{
    __shared__ _Float16 Hs1[16 * 520];
    __shared__ _Float16 Hs2[16 * 520];
    __shared__ float G1S[512];
    __shared__ float Dlds[3][32 * 17];
    __shared__ float C1S[128];
    __shared__ float C2S[128];

    const int bk = blockIdx.x;
    const int tid = threadIdx.x;
    const int w = tid >> 6, lane = tid & 63;

    if (tid < 128) { C1S[tid] = 0.f; C2S[tid] = 0.f; }

    float bs[4][2];
    if (tid >= 64 && tid < 128) {
        int up = (tid - 64) >> 4;
#pragma unroll
        for (int q = 0; q < 4; ++q)
#pragma unroll
            for (int j = 0; j < 2; ++j) {
                int u = bk * 8 + up * 2 + j;
                bs[q][j] = bih[q * 512 + u] + bhh[q * 512 + u];
            }
    }

    const int p = w >> 1, rt = w & 1;
    const int mat = (p == 1) ? 0 : 1;
    const ushort_t* wbase = wprep + (((size_t)(mat * 2048 + bk * 32 + rt * 16)) * 64 + lane) * 8;
    const int boff = (lane & 15) * 520 + (lane >> 4) * 8;
    const int drow0 = rt * 16 + (lane >> 4) * 4, dcol = lane & 15;

    for (int k = 0; k <= NS; ++k) {
        const bool doC1 = (k < NS);
        const bool doC2 = (k > 0);
        {
#pragma unroll
            for (int j = 0; j < 2; ++j) {
                int idx = tid + j * 512;
                int batch = idx >> 6, off = (idx & 63) * 8;
                uint4 v1 = *(const uint4*)(h1h + (size_t)k * 8192 + idx * 8);
                *(uint4*)(Hs1 + batch * 520 + off) = v1;
                if (doC2) {
                    uint4 v2 = *(const uint4*)(h2h + (size_t)(k - 1) * 8192 + idx * 8);
                    *(uint4*)(Hs2 + batch * 520 + off) = v2;
                }
            }
            if (doC1) {
                int r = tid >> 4, bb = tid & 15;
                int n = (r >> 3) * 512 + bk * 8 + (r & 7);
                G1S[tid] = g1x[(size_t)(k * 16 + bb) * 2048 + n];
            }
        }
        __syncthreads();
        if (w < 6 && (p == 0 ? doC1 : doC2)) {
            const _Float16* hs = (p == 2) ? Hs2 : Hs1;
            f32x4 acc = {0.f, 0.f, 0.f, 0.f};
#pragma unroll
            for (int ks = 0; ks < 16; ++ks) {
                f16x8 a = *(const f16x8*)(wbase + (size_t)ks * 512);
                f16x8 b = *(const f16x8*)(hs + boff + ks * 32);
                acc = __builtin_amdgcn_mfma_f32_16x16x32_f16(a, b, acc, 0, 0, 0);
            }
#pragma unroll
            for (int r = 0; r < 4; ++r)
                Dlds[p][(drow0 + r) * 17 + dcol] = acc[r];
        }
        __syncthreads();
        if (tid < 64) {
            if (doC1) {
                int bb = tid & 15, up = tid >> 4;
                unsigned pk = 0;
#pragma unroll
                for (int j = 0; j < 2; ++j) {
                    int ul = up * 2 + j;
                    float gi = G1S[(0 * 8 + ul) * 16 + bb] + Dlds[0][(0 * 8 + ul) * 17 + bb];
                    float gf = G1S[(1 * 8 + ul) * 16 + bb] + Dlds[0][(1 * 8 + ul) * 17 + bb];
                    float gg = G1S[(2 * 8 + ul) * 16 + bb] + Dlds[0][(2 * 8 + ul) * 17 + bb];
                    float go = G1S[(3 * 8 + ul) * 16 + bb] + Dlds[0][(3 * 8 + ul) * 17 + bb];
                    float cn = fsig(gf) * C1S[bb * 8 + ul] + fsig(gi) * ftanhf(gg);
                    C1S[bb * 8 + ul] = cn;
                    _Float16 hv = (_Float16)(fsig(go) * ftanhf(cn));
                    pk |= (unsigned)__builtin_bit_cast(ushort_t, hv) << (16 * j);
                }
                unsigned* dst = (unsigned*)h1h;
                __hip_atomic_store(&dst[(size_t)((k + 1) * 16 + bb) * 256 + bk * 4 + up],
                                   pk, __ATOMIC_RELAXED, __HIP_MEMORY_SCOPE_AGENT);
            }
        } else if (tid < 128) {
            if (doC2) {
                int t2 = tid - 64;
                int bb = t2 & 15, up = t2 >> 4;
                unsigned pk = 0;
#pragma unroll
                for (int j = 0; j < 2; ++j) {
                    int ul = up * 2 + j;
                    float gi = bs[0][j] + Dlds[1][(0 * 8 + ul) * 17 + bb] + Dlds[2][(0 * 8 + ul) * 17 + bb];
                    float gf = bs[1][j] + Dlds[1][(1 * 8 + ul) * 17 + bb] + Dlds[2][(1 * 8 + ul) * 17 + bb];
                    float gg = bs[2][j] + Dlds[1][(2 * 8 + ul) * 17 + bb] + Dlds[2][(2 * 8 + ul) * 17 + bb];
                    float go = bs[3][j] + Dlds[1][(3 * 8 + ul) * 17 + bb] + Dlds[2][(3 * 8 + ul) * 17 + bb];
                    float cn = fsig(gf) * C2S[bb * 8 + ul] + fsig(gi) * ftanhf(gg);
                    C2S[bb * 8 + ul] = cn;
                    _Float16 hv = (_Float16)(fsig(go) * ftanhf(cn));
                    pk |= (unsigned)__builtin_bit_cast(ushort_t, hv) << (16 * j);
                }
                unsigned* dst = (unsigned*)h2h;
                __hip_atomic_store(&dst[(size_t)(k * 16 + bb) * 256 + bk * 4 + up],
                                   pk, __ATOMIC_RELAXED, __HIP_MEMORY_SCOPE_AGENT);
            }
        }
        gbar4(barflags, (unsigned)(k + 1));
    }
}

// ---------------------------------------------------------------------------
// Attention — LDS-staged logits (r16-proven)
// ---------------------------------------------------------------------------
__launch_bounds__(256)
__global__ void attention_k(const _Float16* __restrict__ conv2Vh, const float* __restrict__ hproj,
                            const float* __restrict__ V, const _Float16* __restrict__ Vh,
                            const float* __restrict__ w3, const float* __restrict__ b3,
                            float* __restrict__ attw_out, float* __restrict__ glimpse)
{
    const int r = blockIdx.x;
    const int to = r >> 4, b = r & 15;
    const int tid = threadIdx.x;
    const _Float16* cb = conv2Vh + (size_t)b * 512 * 256;
    const float* hp = hproj + (size_t)r * 512;
    __shared__ _Float16 stg[64 * 264];
    __shared__ float w3S[512];
    __shared__ float red[256];

    w3S[tid]       = w3[tid];
    w3S[tid + 256] = w3[tid + 256];

    const int dl0 = tid >> 5;
    const int pp  = (tid & 31) * 8;

    float a0 = 0.f, a1 = 0.f, a2 = 0.f, a3 = 0.f;
    for (int chunk = 0; chunk < 8; ++chunk) {
        const int dbase = chunk * 64;
        __syncthreads();
#pragma unroll
        for (int j = 0; j < 8; ++j) {
            int dl = j * 8 + dl0;
            int d = dbase + dl;
            f16x8 cv = *(const f16x8*)(cb + (size_t)d * 256 + pp);
            float hpd = hp[d];
            f16x8 t;
#pragma unroll
            for (int e = 0; e < 8; ++e) t[e] = (_Float16)((float)cv[e] + hpd);
            *(f16x8*)&stg[dl * 264 + pp] = t;
        }
        __syncthreads();
#pragma unroll 4
        for (int dl = 0; dl < 64; dl += 4) {
            float x0 = (float)stg[(dl + 0) * 264 + tid];
            float x1 = (float)stg[(dl + 1) * 264 + tid];
            float x2 = (float)stg[(dl + 2) * 264 + tid];
            float x3 = (float)stg[(dl + 3) * 264 + tid];
            a0 = fmaf(w3S[dbase + dl + 0], ftanhf(x0), a0);
            a1 = fmaf(w3S[dbase + dl + 1], ftanhf(x1), a1);
            a2 = fmaf(w3S[dbase + dl + 2], ftanhf(x2), a2);
            a3 = fmaf(w3S[dbase + dl + 3], ftanhf(x3), a3);
        }
    }
    float logit = (a0 + a1) + (a2 + a3) + b3[0];
    __syncthreads();
    red[tid] = logit; __syncthreads();
    for (int s = 128; s > 0; s >>= 1) { if (tid < s) red[tid] = fmaxf(red[tid], red[tid + s]); __syncthreads(); }
    float mx = red[0]; __syncthreads();
    float e = __expf(logit - mx);
    red[tid] = e; __syncthreads();
    for (int s = 128; s > 0; s >>= 1) { if (tid < s) red[tid] += red[tid + s]; __syncthreads(); }
    float aw = e / red[0];
    __syncthreads();
    attw_out[(size_t)b * 10240 + (size_t)to * 256 + tid] = aw;
    red[tid] = aw; __syncthreads();
    if (Vh) {
        const _Float16* Vb = Vh + (size_t)b * 512 * 256;
#pragma unroll
        for (int dl = 0; dl < 2; ++dl) {
            int d = tid + dl * 256;
            float g = 0.f;
            for (int p8 = 0; p8 < 256; p8 += 8) {
                f16x8 vv = *(const f16x8*)(Vb + (size_t)d * 256 + p8);
#pragma unroll
                for (int j = 0; j < 8; ++j)
                    g = fmaf((float)vv[j], red[p8 + j], g);
            }
            glimpse[(size_t)r * 512 + d] = g;
        }
    } else {
        const float* Vb = V + (size_t)b * 512 * 256;
#pragma unroll
        for (int dl = 0; dl < 2; ++dl) {
            int d = tid + dl * 256;
            float g = 0.f;
            for (int p4 = 0; p4 < 256; p4 += 4) {
                float4 vv = *(const float4*)(Vb + (size_t)d * 256 + p4);
                g = fmaf(vv.x, red[p4], g);     g = fmaf(vv.y, red[p4 + 1], g);
                g = fmaf(vv.z, red[p4 + 2], g); g = fmaf(vv.w, red[p4 + 3], g);
            }
            glimpse[(size_t)r * 512 + d] = g;
        }
    }
}

// In-place log_softmax over rows of 7000. grid = 640
__launch_bounds__(256)
__global__ void logsoftmax_k(float* __restrict__ out)
{
    int r = blockIdx.x;
    int b = r & 15, to = r >> 4;
    float* row = out + (size_t)b * 280000 + (size_t)to * 7000;
    __shared__ float buf[7000];
    __shared__ float red[256];
    int tid = threadIdx.x;
    float mx = -1e30f;
    for (int i = tid; i < 7000; i += 256) { float v = row[i]; buf[i] = v; mx = fmaxf(mx, v); }
    red[tid] = mx; __syncthreads();
    for (int s = 128; s > 0; s >>= 1) { if (tid < s) red[tid] = fmaxf(red[tid], red[tid + s]); __syncthreads(); }
    mx = red[0]; __syncthreads();
    float sm = 0.f;
    for (int i = tid; i < 7000; i += 256) sm += __expf(buf[i] - mx);
    red[tid] = sm; __syncthreads();
    for (int s = 128; s > 0; s >>= 1) { if (tid < s) red[tid] += red[tid + s]; __syncthreads(); }
    float lse = mx + __logf(red[0]);
    for (int i = tid; i < 7000; i += 256) row[i] = buf[i] - lse;
}

// ---------------------------------------------------------------------------
extern "C" void kernel_launch(void* const* d_in, const int* in_sizes, int n_in,
                              void* d_out, int out_size, void* d_ws, size_t ws_size,
                              hipStream_t stream)
{
    const float* hw      = (const float*)d_in[0];
    const float* y       = (const float*)d_in[1];
    const float* V       = (const float*)d_in[2];
    const float* w_lin1  = (const float*)d_in[3];
    const float* b_lin1  = (const float*)d_in[4];
    const float* W_ih    = (const float*)d_in[5];
    const float* b_ih    = (const float*)d_in[6];
    const float* W_hh    = (const float*)d_in[7];
    const float* b_hh    = (const float*)d_in[8];
    const float* w_conv1 = (const float*)d_in[9];
    const float* b_conv1 = (const float*)d_in[10];
    const float* w_conv2 = (const float*)d_in[11];
    const float* b_conv2 = (const float*)d_in[12];
    const float* w_conv3 = (const float*)d_in[13];
    const float* b_conv3 = (const float*)d_in[14];
    const float* w_lin2  = (const float*)d_in[15];
    const float* b_lin2  = (const float*)d_in[16];
    float* out = (float*)d_out;

    float* ws = (float*)d_ws;
    // persistent layout (float offsets) — r13/r15/r16-proven schedule
    float* xs_tf   = ws + 0;                         // 319,488 (fallback accum)
    unsigned* barflags = (unsigned*)(ws + 319488);   // 4,096 uints
    float* xs      = ws + 323584;                    // 335,872
    float* g1x     = ws + 659456;                    // 1,343,488
    ushort_t* conv2Vh = (ushort_t*)(ws + 2002944);   // 1,048,576 f
    ushort_t* wconv   = (ushort_t*)(ws + 3051520);   // 1,179,648 f
    float* hproj   = ws + 4231168;                   // 327,680
    float* glimpse = ws + 4558848;                   // 327,680
    ushort_t* h1h  = (ushort_t*)(ws + 5541888);      // 172,032 f
    ushort_t* h2h  = (ushort_t*)(ws + 5713920);      // 172,032 f
    float* w2lh_f  = ws + 5885952;                   // 3,584,000 -> 9,469,952
    ushort_t* w2lh = (ushort_t*)w2lh_f;
    ushort_t* Vh   = (ushort_t*)(ws + 9469952);      // 524,288 -> 9,994,240
    // transient aliases (r13 schedule)
    ushort_t* yh   = (ushort_t*)(ws + 659456);       // dead after y-gemm
    ushort_t* wlh  = (ushort_t*)(ws + 2855936);      // part of yh block
    float* slabs   = w2lh_f;                         // dead after build_xs
    ushort_t* wprep = (ushort_t*)(ws + 4231168);     // aliases hproj; dead after lstm
    const bool big = ws_size >= (size_t)9994240 * sizeof(float);

    // fallback path still needs the atomic accumulator zeroed
    if (!big)
        hipMemsetAsync(ws, 0, (size_t)319488 * sizeof(float), stream);

    // MEGA-PREP: cvt_yw || weight fragment prep || zero(barflags,h slot0)
    mega_prep<<<3313, 256, 0, stream>>>(y, w_lin1, yh, w_conv2, wconv,
                                        W_ih, W_hh, wprep, barflags, h1h, h2h);

    // xs_tf/slabs = y @ w_lin1^T (624x512, K=7040, split-K=8)
    if (big) {
        gemm16<<<dim3(10, 8, 8), 256, 0, stream>>>(nullptr, (const _Float16*)yh,
                                                   nullptr, (const _Float16*)wlh,
                                                   slabs, 624, 512, 7040, 7040, 7040, 512,
                                                   nullptr, nullptr, 0, 8, 1, 319488, 0);
        build_xs<<<656, 256, 0, stream>>>(hw, slabs, w_lin1, b_lin1, xs, 8);
        cvt16<<<1024, 256, 0, stream>>>(w_lin2, w2lh, 7000, 1024, 1024);  // overwrites slabs
    } else {
        gemm16<<<dim3(10, 8, 8), 256, 0, stream>>>(nullptr, (const _Float16*)yh,
                                                   nullptr, (const _Float16*)wlh,
                                                   xs_tf, 624, 512, 7040, 7040, 7040, 512,
                                                   nullptr, nullptr, 0, 8, 0, 0, 0);
        build_xs<<<656, 256, 0, stream>>>(hw, xs_tf, w_lin1, b_lin1, xs, 1);
    }

    // fused: g1x = xs @ W_ih^T + biases  ||  conv2Vh = conv3x3(V) (+Vh persist)
    g1x_conv_fused<<<608, 256, 0, stream>>>(xs, W_ih, g1x, b_ih, b_hh,
                                            V, wconv, b_conv2, conv2Vh,
                                            big ? Vh : nullptr);

    // sequential recurrence (r9 structure)
    void* args[] = {(void*)&g1x, (void*)&wprep, (void*)&b_ih, (void*)&b_hh,
                    (void*)&h1h, (void*)&h2h, (void*)&barflags};
    hipLaunchCooperativeKernel((void*)lstm_rec, dim3(LSTM_NB), dim3(512), args, 0, stream);

    // hproj = h2[1..40] @ w1^T + b_conv1  (MFMA, 80 blocks — wprep dead now)
    gemm16<<<dim3(10, 8), 256, 0, stream>>>(nullptr, (const _Float16*)h2h + 32 * 512,
                                            w_conv1, nullptr,
                                            hproj, 640, 512, 512, 512, 512, 512,
                                            b_conv1, nullptr, 0, 1, 0, 0, 0);
    // attention (LDS-staged; writes attw directly to output region)
    attention_k<<<640, 256, 0, stream>>>((const _Float16*)conv2Vh, hproj, V,
                                         big ? (const _Float16*)Vh : nullptr,
                                         w_conv3, b_conv3, out + 4480000, glimpse);
    // logits: A = virtual [h2 | glimpse]; B = w_lin2 (f16 if big)
    if (big)
        gemm16<<<dim3(10, 110), 256, 0, stream>>>(glimpse, (const _Float16*)h2h + 32 * 512,
                                                  nullptr, (const _Float16*)w2lh,
                                                  out, 640, 7000, 1024, 1024, 1024, 7000,
                                                  b_lin2, nullptr, 2, 1, 0, 0, 1);
    else
        gemm16<<<dim3(10, 110), 256, 0, stream>>>(glimpse, (const _Float16*)h2h + 32 * 512,
                                                  w_lin2, nullptr,
                                                  out, 640, 7000, 1024, 1024, 1024, 7000,
                                                  b_lin2, nullptr, 2, 1, 0, 0, 1);
    logsoftmax_k<<<640, 256, 0, stream>>>(out);
}